// Round 14
// baseline (233.407 us; speedup 1.0000x reference)
//
#include <hip/hip_runtime.h>
#include <hip/hip_bf16.h>
#include <string.h>

typedef __attribute__((ext_vector_type(8))) short short8;
typedef __attribute__((ext_vector_type(4))) float f32x4;
typedef __attribute__((ext_vector_type(4))) float float4v;
typedef __attribute__((ext_vector_type(2))) float float2v;
typedef __attribute__((ext_vector_type(4))) unsigned short ushort4v;

#define LOG2E 1.44269504088896340736f
#define NB 8
#define NN 2048
#define NF 128
#define PKW (NN / 64)
#define PKWORDS (NB * NN * PKW)
#define NGEMMB 256
#define NPACKB 1024

// fast RNE f32->bf16 (finite inputs only)
static __device__ inline unsigned short f2bf(float x) {
    unsigned u = __float_as_uint(x);
    return (unsigned short)((u + 0x7FFFu + ((u >> 16) & 1u)) >> 16);
}
static __device__ inline float bf2f(unsigned short u) {
    union { unsigned u; float f; } v;
    v.u = ((unsigned)u) << 16;
    return v.f;
}
static __device__ inline float fexp2(float x) {
    float r;
    asm("v_exp_f32 %0, %1" : "=v"(r) : "v"(x));
    return r;
}
static __device__ inline unsigned fkey(float f) {
    unsigned u = __float_as_uint(f);
    return (u & 0x80000000u) ? ~u : (u | 0x80000000u);
}
static __device__ inline float funkey(unsigned k) {
    unsigned b = (k & 0x80000000u) ? (k & 0x7FFFFFFFu) : ~k;
    return __uint_as_float(b);
}
static __device__ inline int wave_sniff(const unsigned short* __restrict__ raw) {
    int lane = threadIdx.x & 63;
    int cnt = 0;
#pragma unroll
    for (int i = 0; i < 8; ++i) {
        int e = (raw[lane * 8 + i] >> 7) & 0xFF;
        cnt += (e >= 102 && e <= 139) ? 1 : 0;
    }
#pragma unroll
    for (int off = 1; off < 64; off <<= 1) cnt += __shfl_xor(cnt, off);
    return cnt >= 450;
}

// ---------------- k_prep: WT hi/lo split-transpose + a vectors + init -------
__global__ __launch_bounds__(256) void k_prep(const void* __restrict__ Wraw,
                                              const void* __restrict__ araw,
                                              short* __restrict__ WThi,
                                              short* __restrict__ WTlo,
                                              float* __restrict__ a1s,
                                              float* __restrict__ a2s,
                                              unsigned* __restrict__ s2mkey,
                                              int* __restrict__ cnt) {
    const int bf16w = wave_sniff((const unsigned short*)Wraw);
    int idx = blockIdx.x * 256 + threadIdx.x;
    int k = idx >> 7, n = idx & 127;
    float x = bf16w ? bf2f(((const unsigned short*)Wraw)[idx])
                    : ((const float*)Wraw)[idx];
    unsigned short hi = f2bf(x);
    float lo = x - bf2f(hi);
    WThi[n * 128 + k] = (short)hi;
    WTlo[n * 128 + k] = (short)f2bf(lo);
    if (idx < NB * 128) cnt[idx] = 0;           // finisher counters (1024)
    if (blockIdx.x == 0) {
        int i = threadIdx.x;
        float av = bf16w ? bf2f(((const unsigned short*)araw)[i])
                         : ((const float*)araw)[i];
        if (i < 128) a1s[i] = LOG2E * av;
        else a2s[i - 128] = LOG2E * av;
        if (i < NB) s2mkey[i] = 0u;
    }
}

// ---------------- k_fat: gemm (blocks 0..255) || pack (blocks 256..1279) ----
__global__ __launch_bounds__(256, 4) void k_fat(const int* __restrict__ adj,
                                                unsigned long long* __restrict__ pk,
                                                const void* __restrict__ hraw,
                                                const short* __restrict__ WThi,
                                                const short* __restrict__ WTlo,
                                                const float* __restrict__ a1s,
                                                const float* __restrict__ a2s,
                                                float* __restrict__ s1,
                                                float* __restrict__ EF,
                                                unsigned* __restrict__ s2mkey,
                                                short* __restrict__ WhT) {
    const int tid = threadIdx.x;
    if (blockIdx.x >= NGEMMB) {
        // ---- pack: contiguous 32KB stream per wave (R13-proven) ----
        const int wid = (blockIdx.x - NGEMMB) * 4 + (tid >> 6);
        const int lane = tid & 63;
        const int wpw = PKWORDS / 4096;
        const size_t w0 = (size_t)wid * wpw;
        for (int i = 0; i < wpw; i += 4) {
            int v0 = adj[((w0 + i) << 6) | lane];
            int v1 = adj[((w0 + i + 1) << 6) | lane];
            int v2 = adj[((w0 + i + 2) << 6) | lane];
            int v3 = adj[((w0 + i + 3) << 6) | lane];
            unsigned long long m0 = __ballot(v0 > 0);
            unsigned long long m1 = __ballot(v1 > 0);
            unsigned long long m2 = __ballot(v2 > 0);
            unsigned long long m3 = __ballot(v3 > 0);
            if (lane == 0) {
                pk[w0 + i] = m0;
                pk[w0 + i + 1] = m1;
                pk[w0 + i + 2] = m2;
                pk[w0 + i + 3] = m3;
            }
        }
        return;
    }
    // ---- gemm: Wh + s1 + EF=(2^s2', 2^0.2s2') + s2max (R13-proven) ----
    const int lane = tid & 63;
    const int w = tid >> 6;
    const int lo = lane & 15, g = lane >> 4;
    const int i0 = (blockIdx.x * 4 + w) * 16;
    const int bf16w = wave_sniff((const unsigned short*)hraw);

    short8 ahi[4], alo[4];
    if (bf16w) {
        const short* h16 = (const short*)hraw;
#pragma unroll
        for (int kc = 0; kc < 4; ++kc) {
            ahi[kc] = *(const short8*)(h16 + (size_t)(i0 + lo) * NF + kc * 32 + g * 8);
            alo[kc] = (short8){0, 0, 0, 0, 0, 0, 0, 0};
        }
    } else {
        const float* hf = (const float*)hraw;
#pragma unroll
        for (int kc = 0; kc < 4; ++kc) {
            const float* p = hf + (size_t)(i0 + lo) * NF + kc * 32 + g * 8;
            float4v x0 = *(const float4v*)(p);
            float4v x1 = *(const float4v*)(p + 4);
            short8 h8, l8;
#pragma unroll
            for (int q = 0; q < 4; ++q) {
                unsigned short u0 = f2bf(x0[q]);
                h8[q] = (short)u0;
                l8[q] = (short)f2bf(x0[q] - bf2f(u0));
                unsigned short u1 = f2bf(x1[q]);
                h8[q + 4] = (short)u1;
                l8[q + 4] = (short)f2bf(x1[q] - bf2f(u1));
            }
            ahi[kc] = h8;
            alo[kc] = l8;
        }
    }

    f32x4 acc[8];
#pragma unroll
    for (int t = 0; t < 8; ++t) acc[t] = (f32x4){0.f, 0.f, 0.f, 0.f};
#pragma unroll
    for (int t = 0; t < 8; ++t) {
#pragma unroll
        for (int kc = 0; kc < 4; ++kc) {
            const size_t boff = (size_t)(lo + 16 * t) * NF + kc * 32 + g * 8;
            short8 bhi = *(const short8*)(WThi + boff);
            short8 blo = *(const short8*)(WTlo + boff);
            acc[t] = __builtin_amdgcn_mfma_f32_16x16x32_bf16(ahi[kc], bhi, acc[t], 0, 0, 0);
            acc[t] = __builtin_amdgcn_mfma_f32_16x16x32_bf16(ahi[kc], blo, acc[t], 0, 0, 0);
            acc[t] = __builtin_amdgcn_mfma_f32_16x16x32_bf16(alo[kc], bhi, acc[t], 0, 0, 0);
        }
    }

    const int b = i0 >> 11;
    const int n0 = i0 & 2047;
    short* wt = WhT + (size_t)b * NF * NN;
#pragma unroll
    for (int t = 0; t < 8; ++t) {
        ushort4v u;
#pragma unroll
        for (int r = 0; r < 4; ++r) u[r] = f2bf(acc[t][r]);
        *(ushort4v*)(wt + (size_t)(lo + 16 * t) * NN + n0 + g * 4) = u;
    }

    float a1f[8], a2f[8];
#pragma unroll
    for (int t = 0; t < 8; ++t) {
        a1f[t] = a1s[lo + 16 * t];
        a2f[t] = a2s[lo + 16 * t];
    }
    float wm = -1e30f;
#pragma unroll
    for (int r = 0; r < 4; ++r) {
        float d1 = 0.f, d2 = 0.f;
#pragma unroll
        for (int t = 0; t < 8; ++t) {
            float wv = acc[t][r];
            d1 += wv * a1f[t];
            d2 += wv * a2f[t];
        }
#pragma unroll
        for (int off = 1; off < 16; off <<= 1) {
            d1 += __shfl_xor(d1, off);
            d2 += __shfl_xor(d2, off);
        }
        if (lo == 0) {
            s1[i0 + g * 4 + r] = d1;
            float2v ef;
            ef[0] = fexp2(d2);
            ef[1] = fexp2(0.2f * d2);
            *(float2v*)(EF + (size_t)(i0 + g * 4 + r) * 2) = ef;
        }
        wm = fmaxf(wm, d2);
    }
    wm = fmaxf(wm, __shfl_xor(wm, 16));
    wm = fmaxf(wm, __shfl_xor(wm, 32));
    if (lane == 0) atomicMax(&s2mkey[b], fkey(wm));
}

// ---------------- k_attn: factorized softmax + PV + split-K finisher --------
template <int FINAL, int JS>
__global__ __launch_bounds__(256, 4) void k_attn(const unsigned long long* __restrict__ pk,
                                                 const float* __restrict__ s1,
                                                 const float* __restrict__ EF,
                                                 const unsigned* __restrict__ s2mkey,
                                                 const short* __restrict__ WhT,
                                                 const void* __restrict__ hraw,
                                                 void* __restrict__ out,
                                                 float* __restrict__ pO,
                                                 float* __restrict__ pL,
                                                 int* __restrict__ cnt) {
    constexpr int JL = NN / JS;
    constexpr int NT = JL / 64;

    const int tid = threadIdx.x;
    const int lane = tid & 63, wid = tid >> 6;
    const int lo = lane & 15, g = lane >> 4;
    const int gid = blockIdx.x;
    const int js = (JS > 1) ? (gid / (NB * 32)) : 0;
    const int rem = gid % (NB * 32);
    const int blk = rem & 31;
    const int b = rem >> 5;
    const int rowbase = blk * 64 + wid * 16;
    const int row = rowbase + lo;
    const int jbeg = js * JL;

    __shared__ short lds[2][128 * 64];
    __shared__ float ldsZ[JL * 2];

    const float s1v = s1[b * NN + row];
    const float tm = s1v + funkey(s2mkey[b]);
    const float M = fmaxf(tm, 0.2f * tm);
    const float Tc = fexp2(-s1v);
    const float Ac = fexp2(s1v - M);
    const float Bc = fexp2(0.2f * s1v - M);
    const unsigned long long* pkr = pk + (size_t)(b * NN + row) * PKW + (jbeg >> 6);
    const short* vb = WhT + (size_t)b * NF * NN;

    {
        const float4v* src = (const float4v*)(EF + (size_t)(b * NN + jbeg) * 2);
        for (int i = tid; i < JL / 2; i += 256) ((float4v*)ldsZ)[i] = src[i];
    }

    const int sf = tid >> 1;
    const int sh = tid & 1;
    const short* sbase = vb + (size_t)sf * NN + jbeg + sh * 32;
    char* ldsc0 = (char*)&lds[0][0];
    char* ldsc1 = (char*)&lds[1][0];
    const unsigned swz = (unsigned)((sf & 7) << 4);
    const unsigned wb0 = (unsigned)(sf * 128 + sh * 64);
    const unsigned rsw = (unsigned)((lo & 7) << 4);

    f32x4 acc[8];
#pragma unroll
    for (int t = 0; t < 8; ++t) acc[t] = (f32x4){0.f, 0.f, 0.f, 0.f};
    float lsum = 0.f;

    {
        short8 s0 = *(const short8*)(sbase);
        short8 s1r = *(const short8*)(sbase + 8);
        short8 s2r = *(const short8*)(sbase + 16);
        short8 s3r = *(const short8*)(sbase + 24);
        *(short8*)(ldsc0 + ((wb0 + 0) ^ swz)) = s0;
        *(short8*)(ldsc0 + ((wb0 + 16) ^ swz)) = s1r;
        *(short8*)(ldsc0 + ((wb0 + 32) ^ swz)) = s2r;
        *(short8*)(ldsc0 + ((wb0 + 48) ^ swz)) = s3r;
    }
    unsigned long long mcur = pkr[0];
    __syncthreads();

    int cur = 0;
    for (int t = 0; t < NT; ++t) {
        short8 sn0, sn1, sn2, sn3;
        unsigned long long mnext = 0;
        const bool more = (t + 1 < NT);
        if (more) {
            const short* sp = sbase + (t + 1) * 64;
            sn0 = *(const short8*)(sp);
            sn1 = *(const short8*)(sp + 8);
            sn2 = *(const short8*)(sp + 16);
            sn3 = *(const short8*)(sp + 24);
            mnext = pkr[t + 1];
        }
        const char* cb = cur ? ldsc1 : ldsc0;

        short8 pa[2];
#pragma unroll
        for (int c = 0; c < 2; ++c) {
            const float4v* zp = (const float4v*)&ldsZ[((t) * 64 + c * 32 + g * 8) * 2];
            float4v w_[4];
#pragma unroll
            for (int q = 0; q < 4; ++q) w_[q] = zp[q];
            const unsigned bits = (unsigned)(mcur >> (c * 32 + g * 8)) & 0xFFu;
            float pv[8];
#pragma unroll
            for (int k = 0; k < 8; ++k) {
                float E = w_[k >> 1][(k & 1) * 2];
                float F = w_[k >> 1][(k & 1) * 2 + 1];
                bool cond = E >= Tc;
                float sel = cond ? E : F;
                float coef = cond ? Ac : Bc;
                float p = sel * coef;
                p = ((bits >> k) & 1u) ? p : 0.f;
                lsum += p;
                pv[k] = p;
            }
            unsigned r0, r1, r2, r3;
            asm("v_cvt_pk_bf16_f32 %0, %1, %2" : "=v"(r0) : "v"(pv[0]), "v"(pv[1]));
            asm("v_cvt_pk_bf16_f32 %0, %1, %2" : "=v"(r1) : "v"(pv[2]), "v"(pv[3]));
            asm("v_cvt_pk_bf16_f32 %0, %1, %2" : "=v"(r2) : "v"(pv[4]), "v"(pv[5]));
            asm("v_cvt_pk_bf16_f32 %0, %1, %2" : "=v"(r3) : "v"(pv[6]), "v"(pv[7]));
            union { unsigned u[4]; short8 s; } uu;
            uu.u[0] = r0; uu.u[1] = r1; uu.u[2] = r2; uu.u[3] = r3;
            pa[c] = uu.s;
        }

#pragma unroll
        for (int t8 = 0; t8 < 8; ++t8) {
            const unsigned rb0 = ((unsigned)((lo + 16 * t8) * 128 + g * 16)) ^ rsw;
            const unsigned rb1 = ((unsigned)((lo + 16 * t8) * 128 + 64 + g * 16)) ^ rsw;
            short8 v0 = *(const short8*)(cb + rb0);
            short8 v1 = *(const short8*)(cb + rb1);
            acc[t8] = __builtin_amdgcn_mfma_f32_16x16x32_bf16(pa[0], v0, acc[t8], 0, 0, 0);
            acc[t8] = __builtin_amdgcn_mfma_f32_16x16x32_bf16(pa[1], v1, acc[t8], 0, 0, 0);
        }

        if (more) {
            char* wb = cur ? ldsc0 : ldsc1;
            *(short8*)(wb + ((wb0 + 0) ^ swz)) = sn0;
            *(short8*)(wb + ((wb0 + 16) ^ swz)) = sn1;
            *(short8*)(wb + ((wb0 + 32) ^ swz)) = sn2;
            *(short8*)(wb + ((wb0 + 48) ^ swz)) = sn3;
            mcur = mnext;
        }
        __syncthreads();
        cur ^= 1;
    }

    lsum += __shfl_xor(lsum, 16);
    lsum += __shfl_xor(lsum, 32);

    if (FINAL) {
        const int bf16w = wave_sniff((const unsigned short*)hraw);
        float inv[4];
#pragma unroll
        for (int r = 0; r < 4; ++r) inv[r] = 1.0f / __shfl(lsum, g * 4 + r);
#pragma unroll
        for (int t8 = 0; t8 < 8; ++t8) {
#pragma unroll
            for (int r = 0; r < 4; ++r) {
                float x = acc[t8][r] * inv[r];
                float y = (x > 0.f) ? x : (fexp2(x * LOG2E) - 1.0f);
                size_t oi = ((size_t)b * NN + rowbase + g * 4 + r) * NF + lo + 16 * t8;
                if (bf16w) ((unsigned short*)out)[oi] = f2bf(y);
                else ((float*)out)[oi] = y;
            }
        }
    } else {
        const int grp = b * 128 + blk * 4 + wid;
        float* po = pO + (size_t)(grp * JS + js) * (16 * NF);
#pragma unroll
        for (int t8 = 0; t8 < 8; ++t8)
#pragma unroll
            for (int r = 0; r < 4; ++r)
                po[(g * 4 + r) * NF + lo + 16 * t8] = acc[t8][r];
        if (g == 0) pL[(grp * JS + js) * 16 + lo] = lsum;

        // ---- split-K last-finisher: combine this group's JS partials ----
        __threadfence();
        int old = 0;
        if (lane == 0) old = atomicAdd(&cnt[grp], 1);
        old = __shfl(old, 0);
        if (old == JS - 1) {
            __threadfence();
            const int bf16w = wave_sniff((const unsigned short*)hraw);
            const int col = (lane & 31) * 4 + (lane >> 5) * 0;  // 2 rows/pass
            // each pass: 2 rows x 128 cols; lane covers (row=lane>>5? no) --
            // simpler: 16 rows; per row, 64 lanes x 2 cols (float2)
            for (int r = 0; r < 16; ++r) {
                float l = 0.f;
#pragma unroll
                for (int jx = 0; jx < JS; ++jx)
                    l += pL[(grp * JS + jx) * 16 + r];
                const float inv = 1.0f / l;
                float2v o = (float2v){0.f, 0.f};
#pragma unroll
                for (int jx = 0; jx < JS; ++jx)
                    o += *(const float2v*)(pO + (size_t)(grp * JS + jx) * (16 * NF) +
                                           r * NF + lane * 2);
                float y0 = o[0] * inv, y1 = o[1] * inv;
                y0 = (y0 > 0.f) ? y0 : (fexp2(y0 * LOG2E) - 1.0f);
                y1 = (y1 > 0.f) ? y1 : (fexp2(y1 * LOG2E) - 1.0f);
                size_t ob = ((size_t)b * NN + rowbase + r) * NF + lane * 2;
                if (bf16w) {
                    unsigned short u0 = f2bf(y0), u1 = f2bf(y1);
                    unsigned pairu = (unsigned)u0 | ((unsigned)u1 << 16);
                    *(unsigned*)((unsigned short*)out + ob) = pairu;
                } else {
                    *(float2v*)((float*)out + ob) = (float2v){y0, y1};
                }
            }
        }
    }
}

extern "C" void kernel_launch(void* const* d_in, const int* in_sizes, int n_in,
                              void* d_out, int out_size, void* d_ws, size_t ws_size,
                              hipStream_t stream) {
    const void* h = d_in[0];
    const int* adj = (const int*)d_in[1];
    const void* W = d_in[2];
    const void* a = d_in[3];

    char* ws = (char*)d_ws;
    auto align256 = [](size_t x) { return (x + 255) & ~(size_t)255; };
    size_t off = 0;
    short* WThi = (short*)(ws + off); off = align256(off + (size_t)128 * 128 * 2);
    short* WTlo = (short*)(ws + off); off = align256(off + (size_t)128 * 128 * 2);
    float* a1s = (float*)(ws + off);  off = align256(off + 128 * 4);
    float* a2s = (float*)(ws + off);  off = align256(off + 128 * 4);
    short* WhT = (short*)(ws + off);  off = align256(off + (size_t)NB * NF * NN * 2);
    float* s1 = (float*)(ws + off);   off = align256(off + (size_t)NB * NN * 4);
    float* EF = (float*)(ws + off);   off = align256(off + (size_t)NB * NN * 8);
    unsigned* s2mkey = (unsigned*)(ws + off); off = align256(off + NB * 4);
    int* cnt = (int*)(ws + off);      off = align256(off + (size_t)NB * 128 * 4);
    unsigned long long* pk = (unsigned long long*)(ws + off);
    off = align256(off + (size_t)PKWORDS * 8);

    const int ngrp = NB * 128;
    auto need = [&](int js) {
        return off + (size_t)ngrp * js * 16 * NF * 4 + 512 + (size_t)ngrp * js * 16 * 4;
    };
    int jsplit = (ws_size >= need(4)) ? 4 : ((ws_size >= need(2)) ? 2 : 1);
    float* pO = nullptr;
    float* pL = nullptr;
    if (jsplit > 1) {
        size_t pO_bytes = (size_t)ngrp * jsplit * 16 * NF * 4;
        size_t pL_bytes = (size_t)ngrp * jsplit * 16 * 4;
        pO = (float*)(ws + off); off = align256(off + pO_bytes);
        pL = (float*)(ws + off); off = align256(off + pL_bytes);
    }

    k_prep<<<64, 256, 0, stream>>>(W, a, WThi, WTlo, a1s, a2s, s2mkey, cnt);
    k_fat<<<NGEMMB + NPACKB, 256, 0, stream>>>(adj, pk, h, WThi, WTlo, a1s, a2s,
                                               s1, EF, s2mkey, WhT);
    if (jsplit == 4) {
        k_attn<0, 4><<<NB * 32 * 4, 256, 0, stream>>>(pk, s1, EF, s2mkey, WhT, h,
                                                      d_out, pO, pL, cnt);
    } else if (jsplit == 2) {
        k_attn<0, 2><<<NB * 32 * 2, 256, 0, stream>>>(pk, s1, EF, s2mkey, WhT, h,
                                                      d_out, pO, pL, cnt);
    } else {
        k_attn<1, 1><<<NB * 32, 256, 0, stream>>>(pk, s1, EF, s2mkey, WhT, h,
                                                  d_out, nullptr, nullptr, cnt);
    }
}

// Round 15
// 78.538 us; speedup vs baseline: 2.9719x; 2.9719x over previous
//
#include <hip/hip_runtime.h>
#include <hip/hip_bf16.h>
#include <string.h>

typedef __attribute__((ext_vector_type(8))) short short8;
typedef __attribute__((ext_vector_type(4))) float f32x4;
typedef __attribute__((ext_vector_type(4))) float float4v;
typedef __attribute__((ext_vector_type(2))) float float2v;
typedef __attribute__((ext_vector_type(4))) unsigned short ushort4v;

#define LOG2E 1.44269504088896340736f
#define NB 8
#define NN 2048
#define NF 128
#define PKW (NN / 64)
#define PKWORDS (NB * NN * PKW)
#define NGEMMB 256
#define NPACKB 1024

// fast RNE f32->bf16 (finite inputs only)
static __device__ inline unsigned short f2bf(float x) {
    unsigned u = __float_as_uint(x);
    return (unsigned short)((u + 0x7FFFu + ((u >> 16) & 1u)) >> 16);
}
static __device__ inline float bf2f(unsigned short u) {
    union { unsigned u; float f; } v;
    v.u = ((unsigned)u) << 16;
    return v.f;
}
static __device__ inline float fexp2(float x) {
    float r;
    asm("v_exp_f32 %0, %1" : "=v"(r) : "v"(x));
    return r;
}
static __device__ inline unsigned fkey(float f) {
    unsigned u = __float_as_uint(f);
    return (u & 0x80000000u) ? ~u : (u | 0x80000000u);
}
static __device__ inline float funkey(unsigned k) {
    unsigned b = (k & 0x80000000u) ? (k & 0x7FFFFFFFu) : ~k;
    return __uint_as_float(b);
}
static __device__ inline int wave_sniff(const unsigned short* __restrict__ raw) {
    int lane = threadIdx.x & 63;
    int cnt = 0;
#pragma unroll
    for (int i = 0; i < 8; ++i) {
        int e = (raw[lane * 8 + i] >> 7) & 0xFF;
        cnt += (e >= 102 && e <= 139) ? 1 : 0;
    }
#pragma unroll
    for (int off = 1; off < 64; off <<= 1) cnt += __shfl_xor(cnt, off);
    return cnt >= 450;
}

// ---------------- k_prep: WT hi/lo split-transpose + a vectors + s2m init ---
__global__ __launch_bounds__(256) void k_prep(const void* __restrict__ Wraw,
                                              const void* __restrict__ araw,
                                              short* __restrict__ WThi,
                                              short* __restrict__ WTlo,
                                              float* __restrict__ a1s,
                                              float* __restrict__ a2s,
                                              unsigned* __restrict__ s2mkey) {
    const int bf16w = wave_sniff((const unsigned short*)Wraw);
    int idx = blockIdx.x * 256 + threadIdx.x;
    int k = idx >> 7, n = idx & 127;
    float x = bf16w ? bf2f(((const unsigned short*)Wraw)[idx])
                    : ((const float*)Wraw)[idx];
    unsigned short hi = f2bf(x);
    float lo = x - bf2f(hi);
    WThi[n * 128 + k] = (short)hi;
    WTlo[n * 128 + k] = (short)f2bf(lo);
    if (blockIdx.x == 0) {
        int i = threadIdx.x;
        float av = bf16w ? bf2f(((const unsigned short*)araw)[i])
                         : ((const float*)araw)[i];
        if (i < 128) a1s[i] = LOG2E * av;
        else a2s[i - 128] = LOG2E * av;
        if (i < NB) s2mkey[i] = 0u;
    }
}

// ---------------- k_fat: gemm (blocks 0..255) || pack (blocks 256..1279) ----
__global__ __launch_bounds__(256, 4) void k_fat(const int* __restrict__ adj,
                                                unsigned long long* __restrict__ pk,
                                                const void* __restrict__ hraw,
                                                const short* __restrict__ WThi,
                                                const short* __restrict__ WTlo,
                                                const float* __restrict__ a1s,
                                                const float* __restrict__ a2s,
                                                float* __restrict__ s1,
                                                float* __restrict__ EF,
                                                unsigned* __restrict__ s2mkey,
                                                short* __restrict__ WhT) {
    const int tid = threadIdx.x;
    if (blockIdx.x >= NGEMMB) {
        // ---- pack: contiguous 32KB stream per wave (R13-proven shape) ----
        const int wid = (blockIdx.x - NGEMMB) * 4 + (tid >> 6);
        const int lane = tid & 63;
        const int wpw = PKWORDS / 4096;
        const size_t w0 = (size_t)wid * wpw;
        for (int i = 0; i < wpw; i += 4) {
            int v0 = adj[((w0 + i) << 6) | lane];
            int v1 = adj[((w0 + i + 1) << 6) | lane];
            int v2 = adj[((w0 + i + 2) << 6) | lane];
            int v3 = adj[((w0 + i + 3) << 6) | lane];
            unsigned long long m0 = __ballot(v0 > 0);
            unsigned long long m1 = __ballot(v1 > 0);
            unsigned long long m2 = __ballot(v2 > 0);
            unsigned long long m3 = __ballot(v3 > 0);
            if (lane == 0) {
                pk[w0 + i] = m0;
                pk[w0 + i + 1] = m1;
                pk[w0 + i + 2] = m2;
                pk[w0 + i + 3] = m3;
            }
        }
        return;
    }
    // ---- gemm: Wh + s1 + EF=(2^s2', 2^0.2s2') + s2max (R13-proven) ----
    const int lane = tid & 63;
    const int w = tid >> 6;
    const int lo = lane & 15, g = lane >> 4;
    const int i0 = (blockIdx.x * 4 + w) * 16;
    const int bf16w = wave_sniff((const unsigned short*)hraw);

    short8 ahi[4], alo[4];
    if (bf16w) {
        const short* h16 = (const short*)hraw;
#pragma unroll
        for (int kc = 0; kc < 4; ++kc) {
            ahi[kc] = *(const short8*)(h16 + (size_t)(i0 + lo) * NF + kc * 32 + g * 8);
            alo[kc] = (short8){0, 0, 0, 0, 0, 0, 0, 0};
        }
    } else {
        const float* hf = (const float*)hraw;
#pragma unroll
        for (int kc = 0; kc < 4; ++kc) {
            const float* p = hf + (size_t)(i0 + lo) * NF + kc * 32 + g * 8;
            float4v x0 = *(const float4v*)(p);
            float4v x1 = *(const float4v*)(p + 4);
            short8 h8, l8;
#pragma unroll
            for (int q = 0; q < 4; ++q) {
                unsigned short u0 = f2bf(x0[q]);
                h8[q] = (short)u0;
                l8[q] = (short)f2bf(x0[q] - bf2f(u0));
                unsigned short u1 = f2bf(x1[q]);
                h8[q + 4] = (short)u1;
                l8[q + 4] = (short)f2bf(x1[q] - bf2f(u1));
            }
            ahi[kc] = h8;
            alo[kc] = l8;
        }
    }

    f32x4 acc[8];
#pragma unroll
    for (int t = 0; t < 8; ++t) acc[t] = (f32x4){0.f, 0.f, 0.f, 0.f};
#pragma unroll
    for (int t = 0; t < 8; ++t) {
#pragma unroll
        for (int kc = 0; kc < 4; ++kc) {
            const size_t boff = (size_t)(lo + 16 * t) * NF + kc * 32 + g * 8;
            short8 bhi = *(const short8*)(WThi + boff);
            short8 blo = *(const short8*)(WTlo + boff);
            acc[t] = __builtin_amdgcn_mfma_f32_16x16x32_bf16(ahi[kc], bhi, acc[t], 0, 0, 0);
            acc[t] = __builtin_amdgcn_mfma_f32_16x16x32_bf16(ahi[kc], blo, acc[t], 0, 0, 0);
            acc[t] = __builtin_amdgcn_mfma_f32_16x16x32_bf16(alo[kc], bhi, acc[t], 0, 0, 0);
        }
    }

    const int b = i0 >> 11;
    const int n0 = i0 & 2047;
    short* wt = WhT + (size_t)b * NF * NN;
#pragma unroll
    for (int t = 0; t < 8; ++t) {
        ushort4v u;
#pragma unroll
        for (int r = 0; r < 4; ++r) u[r] = f2bf(acc[t][r]);
        *(ushort4v*)(wt + (size_t)(lo + 16 * t) * NN + n0 + g * 4) = u;
    }

    float a1f[8], a2f[8];
#pragma unroll
    for (int t = 0; t < 8; ++t) {
        a1f[t] = a1s[lo + 16 * t];
        a2f[t] = a2s[lo + 16 * t];
    }
    float wm = -1e30f;
#pragma unroll
    for (int r = 0; r < 4; ++r) {
        float d1 = 0.f, d2 = 0.f;
#pragma unroll
        for (int t = 0; t < 8; ++t) {
            float wv = acc[t][r];
            d1 += wv * a1f[t];
            d2 += wv * a2f[t];
        }
#pragma unroll
        for (int off = 1; off < 16; off <<= 1) {
            d1 += __shfl_xor(d1, off);
            d2 += __shfl_xor(d2, off);
        }
        if (lo == 0) {
            s1[i0 + g * 4 + r] = d1;
            float2v ef;
            ef[0] = fexp2(d2);
            ef[1] = fexp2(0.2f * d2);
            *(float2v*)(EF + (size_t)(i0 + g * 4 + r) * 2) = ef;
        }
        wm = fmaxf(wm, d2);
    }
    wm = fmaxf(wm, __shfl_xor(wm, 16));
    wm = fmaxf(wm, __shfl_xor(wm, 32));
    if (lane == 0) atomicMax(&s2mkey[b], fkey(wm));
}

// ---------------- k_attn: factorized softmax (no exp in loop) + PV ----------
// (R13-proven, byte-identical)
template <int FINAL, int JS>
__global__ __launch_bounds__(256, 4) void k_attn(const unsigned long long* __restrict__ pk,
                                                 const float* __restrict__ s1,
                                                 const float* __restrict__ EF,
                                                 const unsigned* __restrict__ s2mkey,
                                                 const short* __restrict__ WhT,
                                                 const void* __restrict__ hraw,
                                                 void* __restrict__ out,
                                                 float* __restrict__ pO,
                                                 float* __restrict__ pL) {
    constexpr int JL = NN / JS;
    constexpr int NT = JL / 64;

    const int tid = threadIdx.x;
    const int lane = tid & 63, wid = tid >> 6;
    const int lo = lane & 15, g = lane >> 4;
    const int gid = blockIdx.x;
    const int js = (JS > 1) ? (gid / (NB * 32)) : 0;
    const int rem = gid % (NB * 32);
    const int blk = rem & 31;
    const int b = rem >> 5;
    const int rowbase = blk * 64 + wid * 16;
    const int row = rowbase + lo;
    const int jbeg = js * JL;

    __shared__ short lds[2][128 * 64];
    __shared__ float ldsZ[JL * 2];

    const float s1v = s1[b * NN + row];
    const float tm = s1v + funkey(s2mkey[b]);
    const float M = fmaxf(tm, 0.2f * tm);
    const float Tc = fexp2(-s1v);
    const float Ac = fexp2(s1v - M);
    const float Bc = fexp2(0.2f * s1v - M);
    const unsigned long long* pkr = pk + (size_t)(b * NN + row) * PKW + (jbeg >> 6);
    const short* vb = WhT + (size_t)b * NF * NN;

    {
        const float4v* src = (const float4v*)(EF + (size_t)(b * NN + jbeg) * 2);
        for (int i = tid; i < JL / 2; i += 256) ((float4v*)ldsZ)[i] = src[i];
    }

    const int sf = tid >> 1;
    const int sh = tid & 1;
    const short* sbase = vb + (size_t)sf * NN + jbeg + sh * 32;
    char* ldsc0 = (char*)&lds[0][0];
    char* ldsc1 = (char*)&lds[1][0];
    const unsigned swz = (unsigned)((sf & 7) << 4);
    const unsigned wb0 = (unsigned)(sf * 128 + sh * 64);
    const unsigned rsw = (unsigned)((lo & 7) << 4);

    f32x4 acc[8];
#pragma unroll
    for (int t = 0; t < 8; ++t) acc[t] = (f32x4){0.f, 0.f, 0.f, 0.f};
    float lsum = 0.f;

    {
        short8 s0 = *(const short8*)(sbase);
        short8 s1r = *(const short8*)(sbase + 8);
        short8 s2r = *(const short8*)(sbase + 16);
        short8 s3r = *(const short8*)(sbase + 24);
        *(short8*)(ldsc0 + ((wb0 + 0) ^ swz)) = s0;
        *(short8*)(ldsc0 + ((wb0 + 16) ^ swz)) = s1r;
        *(short8*)(ldsc0 + ((wb0 + 32) ^ swz)) = s2r;
        *(short8*)(ldsc0 + ((wb0 + 48) ^ swz)) = s3r;
    }
    unsigned long long mcur = pkr[0];
    __syncthreads();

    int cur = 0;
    for (int t = 0; t < NT; ++t) {
        short8 sn0, sn1, sn2, sn3;
        unsigned long long mnext = 0;
        const bool more = (t + 1 < NT);
        if (more) {
            const short* sp = sbase + (t + 1) * 64;
            sn0 = *(const short8*)(sp);
            sn1 = *(const short8*)(sp + 8);
            sn2 = *(const short8*)(sp + 16);
            sn3 = *(const short8*)(sp + 24);
            mnext = pkr[t + 1];
        }
        const char* cb = cur ? ldsc1 : ldsc0;

        short8 pa[2];
#pragma unroll
        for (int c = 0; c < 2; ++c) {
            const float4v* zp = (const float4v*)&ldsZ[((t) * 64 + c * 32 + g * 8) * 2];
            float4v w_[4];
#pragma unroll
            for (int q = 0; q < 4; ++q) w_[q] = zp[q];
            const unsigned bits = (unsigned)(mcur >> (c * 32 + g * 8)) & 0xFFu;
            float pv[8];
#pragma unroll
            for (int k = 0; k < 8; ++k) {
                float E = w_[k >> 1][(k & 1) * 2];
                float F = w_[k >> 1][(k & 1) * 2 + 1];
                bool cond = E >= Tc;
                float sel = cond ? E : F;
                float coef = cond ? Ac : Bc;
                float p = sel * coef;
                p = ((bits >> k) & 1u) ? p : 0.f;
                lsum += p;
                pv[k] = p;
            }
            unsigned r0, r1, r2, r3;
            asm("v_cvt_pk_bf16_f32 %0, %1, %2" : "=v"(r0) : "v"(pv[0]), "v"(pv[1]));
            asm("v_cvt_pk_bf16_f32 %0, %1, %2" : "=v"(r1) : "v"(pv[2]), "v"(pv[3]));
            asm("v_cvt_pk_bf16_f32 %0, %1, %2" : "=v"(r2) : "v"(pv[4]), "v"(pv[5]));
            asm("v_cvt_pk_bf16_f32 %0, %1, %2" : "=v"(r3) : "v"(pv[6]), "v"(pv[7]));
            union { unsigned u[4]; short8 s; } uu;
            uu.u[0] = r0; uu.u[1] = r1; uu.u[2] = r2; uu.u[3] = r3;
            pa[c] = uu.s;
        }

#pragma unroll
        for (int t8 = 0; t8 < 8; ++t8) {
            const unsigned rb0 = ((unsigned)((lo + 16 * t8) * 128 + g * 16)) ^ rsw;
            const unsigned rb1 = ((unsigned)((lo + 16 * t8) * 128 + 64 + g * 16)) ^ rsw;
            short8 v0 = *(const short8*)(cb + rb0);
            short8 v1 = *(const short8*)(cb + rb1);
            acc[t8] = __builtin_amdgcn_mfma_f32_16x16x32_bf16(pa[0], v0, acc[t8], 0, 0, 0);
            acc[t8] = __builtin_amdgcn_mfma_f32_16x16x32_bf16(pa[1], v1, acc[t8], 0, 0, 0);
        }

        if (more) {
            char* wb = cur ? ldsc0 : ldsc1;
            *(short8*)(wb + ((wb0 + 0) ^ swz)) = sn0;
            *(short8*)(wb + ((wb0 + 16) ^ swz)) = sn1;
            *(short8*)(wb + ((wb0 + 32) ^ swz)) = sn2;
            *(short8*)(wb + ((wb0 + 48) ^ swz)) = sn3;
            mcur = mnext;
        }
        __syncthreads();
        cur ^= 1;
    }

    lsum += __shfl_xor(lsum, 16);
    lsum += __shfl_xor(lsum, 32);

    if (FINAL) {
        const int bf16w = wave_sniff((const unsigned short*)hraw);
        float inv[4];
#pragma unroll
        for (int r = 0; r < 4; ++r) inv[r] = 1.0f / __shfl(lsum, g * 4 + r);
#pragma unroll
        for (int t8 = 0; t8 < 8; ++t8) {
#pragma unroll
            for (int r = 0; r < 4; ++r) {
                float x = acc[t8][r] * inv[r];
                float y = (x > 0.f) ? x : (fexp2(x * LOG2E) - 1.0f);
                size_t oi = ((size_t)b * NN + rowbase + g * 4 + r) * NF + lo + 16 * t8;
                if (bf16w) ((unsigned short*)out)[oi] = f2bf(y);
                else ((float*)out)[oi] = y;
            }
        }
    } else {
        const int grp = b * 128 + blk * 4 + wid;
        float* po = pO + (size_t)(grp * JS + js) * (16 * NF);
#pragma unroll
        for (int t8 = 0; t8 < 8; ++t8)
#pragma unroll
            for (int r = 0; r < 4; ++r)
                po[(g * 4 + r) * NF + lo + 16 * t8] = acc[t8][r];
        if (g == 0) pL[(grp * JS + js) * 16 + lo] = lsum;
    }
}

// ---------------- k_combine: merge j-split partials, ELU, store (vec4) ------
__global__ __launch_bounds__(256) void k_combine(const float* __restrict__ pO,
                                                 const float* __restrict__ pL,
                                                 const void* __restrict__ hraw,
                                                 void* __restrict__ out,
                                                 int jsplit) {
    const int bf16w = wave_sniff((const unsigned short*)hraw);
    int idx4 = blockIdx.x * 256 + threadIdx.x;
    int base = idx4 * 4;
    if (base >= NB * NN * NF) return;
    int col = base & 127;
    int rowg = base >> 7;
    int r = rowg & 15;
    int grp = rowg >> 4;
    float4v o = (float4v){0.f, 0.f, 0.f, 0.f};
    float l = 0.f;
    for (int js = 0; js < jsplit; ++js) {
        int task = grp * jsplit + js;
        o += *(const float4v*)(pO + (size_t)task * (16 * NF) + r * NF + col);
        l += pL[task * 16 + r];
    }
    float inv = 1.0f / l;
    float y[4];
#pragma unroll
    for (int q = 0; q < 4; ++q) {
        float x = o[q] * inv;
        y[q] = (x > 0.f) ? x : (fexp2(x * LOG2E) - 1.0f);
    }
    if (bf16w) {
        ushort4v u;
#pragma unroll
        for (int q = 0; q < 4; ++q) u[q] = f2bf(y[q]);
        *(ushort4v*)((unsigned short*)out + base) = u;
    } else {
        *(float4v*)((float*)out + base) = (float4v){y[0], y[1], y[2], y[3]};
    }
}

extern "C" void kernel_launch(void* const* d_in, const int* in_sizes, int n_in,
                              void* d_out, int out_size, void* d_ws, size_t ws_size,
                              hipStream_t stream) {
    const void* h = d_in[0];
    const int* adj = (const int*)d_in[1];
    const void* W = d_in[2];
    const void* a = d_in[3];

    char* ws = (char*)d_ws;
    auto align256 = [](size_t x) { return (x + 255) & ~(size_t)255; };
    size_t off = 0;
    short* WThi = (short*)(ws + off); off = align256(off + (size_t)128 * 128 * 2);
    short* WTlo = (short*)(ws + off); off = align256(off + (size_t)128 * 128 * 2);
    float* a1s = (float*)(ws + off);  off = align256(off + 128 * 4);
    float* a2s = (float*)(ws + off);  off = align256(off + 128 * 4);
    short* WhT = (short*)(ws + off);  off = align256(off + (size_t)NB * NF * NN * 2);
    float* s1 = (float*)(ws + off);   off = align256(off + (size_t)NB * NN * 4);
    float* EF = (float*)(ws + off);   off = align256(off + (size_t)NB * NN * 8);
    unsigned* s2mkey = (unsigned*)(ws + off); off = align256(off + NB * 4);
    unsigned long long* pk = (unsigned long long*)(ws + off);
    off = align256(off + (size_t)PKWORDS * 8);

    const int ngrp = NB * 128;
    auto need = [&](int js) {
        return off + (size_t)ngrp * js * 16 * NF * 4 + 512 + (size_t)ngrp * js * 16 * 4;
    };
    int jsplit = (ws_size >= need(4)) ? 4 : ((ws_size >= need(2)) ? 2 : 1);
    float* pO = nullptr;
    float* pL = nullptr;
    if (jsplit > 1) {
        size_t pO_bytes = (size_t)ngrp * jsplit * 16 * NF * 4;
        size_t pL_bytes = (size_t)ngrp * jsplit * 16 * 4;
        pO = (float*)(ws + off); off = align256(off + pO_bytes);
        pL = (float*)(ws + off); off = align256(off + pL_bytes);
    }

    k_prep<<<64, 256, 0, stream>>>(W, a, WThi, WTlo, a1s, a2s, s2mkey);
    k_fat<<<NGEMMB + NPACKB, 256, 0, stream>>>(adj, pk, h, WThi, WTlo, a1s, a2s,
                                               s1, EF, s2mkey, WhT);
    if (jsplit == 4) {
        k_attn<0, 4><<<NB * 32 * 4, 256, 0, stream>>>(pk, s1, EF, s2mkey, WhT, h,
                                                      d_out, pO, pL);
    } else if (jsplit == 2) {
        k_attn<0, 2><<<NB * 32 * 2, 256, 0, stream>>>(pk, s1, EF, s2mkey, WhT, h,
                                                      d_out, pO, pL);
    } else {
        k_attn<1, 1><<<NB * 32, 256, 0, stream>>>(pk, s1, EF, s2mkey, WhT, h,
                                                  d_out, nullptr, nullptr);
    }
    if (jsplit > 1) {
        int nout = NB * NN * NF;
        k_combine<<<(nout / 4 + 255) / 256, 256, 0, stream>>>(pO, pL, h, d_out, jsplit);
    }
}

// Round 16
// 76.126 us; speedup vs baseline: 3.0660x; 1.0317x over previous
//
#include <hip/hip_runtime.h>
#include <hip/hip_bf16.h>
#include <string.h>

typedef __attribute__((ext_vector_type(8))) short short8;
typedef __attribute__((ext_vector_type(4))) float f32x4;
typedef __attribute__((ext_vector_type(4))) float float4v;
typedef __attribute__((ext_vector_type(2))) float float2v;
typedef __attribute__((ext_vector_type(4))) unsigned short ushort4v;

#define LOG2E 1.44269504088896340736f
#define NB 8
#define NN 2048
#define NF 128
#define PKW (NN / 64)
#define PKWORDS (NB * NN * PKW)
#define NGEMMB 256
#define NPACKB 1024

// fast RNE f32->bf16 (finite inputs only)
static __device__ inline unsigned short f2bf(float x) {
    unsigned u = __float_as_uint(x);
    return (unsigned short)((u + 0x7FFFu + ((u >> 16) & 1u)) >> 16);
}
static __device__ inline float bf2f(unsigned short u) {
    union { unsigned u; float f; } v;
    v.u = ((unsigned)u) << 16;
    return v.f;
}
static __device__ inline float fexp2(float x) {
    float r;
    asm("v_exp_f32 %0, %1" : "=v"(r) : "v"(x));
    return r;
}
static __device__ inline unsigned fkey(float f) {
    unsigned u = __float_as_uint(f);
    return (u & 0x80000000u) ? ~u : (u | 0x80000000u);
}
static __device__ inline float funkey(unsigned k) {
    unsigned b = (k & 0x80000000u) ? (k & 0x7FFFFFFFu) : ~k;
    return __uint_as_float(b);
}
static __device__ inline int wave_sniff(const unsigned short* __restrict__ raw) {
    int lane = threadIdx.x & 63;
    int cnt = 0;
#pragma unroll
    for (int i = 0; i < 8; ++i) {
        int e = (raw[lane * 8 + i] >> 7) & 0xFF;
        cnt += (e >= 102 && e <= 139) ? 1 : 0;
    }
#pragma unroll
    for (int off = 1; off < 64; off <<= 1) cnt += __shfl_xor(cnt, off);
    return cnt >= 450;
}

// ---------------- k_prep: WT hi/lo split-transpose + a vectors + s2m init ---
__global__ __launch_bounds__(256) void k_prep(const void* __restrict__ Wraw,
                                              const void* __restrict__ araw,
                                              short* __restrict__ WThi,
                                              short* __restrict__ WTlo,
                                              float* __restrict__ a1s,
                                              float* __restrict__ a2s,
                                              unsigned* __restrict__ s2mkey) {
    const int bf16w = wave_sniff((const unsigned short*)Wraw);
    int idx = blockIdx.x * 256 + threadIdx.x;
    int k = idx >> 7, n = idx & 127;
    float x = bf16w ? bf2f(((const unsigned short*)Wraw)[idx])
                    : ((const float*)Wraw)[idx];
    unsigned short hi = f2bf(x);
    float lo = x - bf2f(hi);
    WThi[n * 128 + k] = (short)hi;
    WTlo[n * 128 + k] = (short)f2bf(lo);
    if (blockIdx.x == 0) {
        int i = threadIdx.x;
        float av = bf16w ? bf2f(((const unsigned short*)araw)[i])
                         : ((const float*)araw)[i];
        if (i < 128) a1s[i] = LOG2E * av;
        else a2s[i - 128] = LOG2E * av;
        if (i < NB) s2mkey[i] = 0u;
    }
}

// ---------------- k_fat: gemm (blocks 0..255) || pack (blocks 256..1279) ----
__global__ __launch_bounds__(256, 4) void k_fat(const int* __restrict__ adj,
                                                unsigned long long* __restrict__ pk,
                                                const void* __restrict__ hraw,
                                                const short* __restrict__ WThi,
                                                const short* __restrict__ WTlo,
                                                const float* __restrict__ a1s,
                                                const float* __restrict__ a2s,
                                                float* __restrict__ s1,
                                                float* __restrict__ EF,
                                                unsigned* __restrict__ s2mkey,
                                                short* __restrict__ WhT) {
    const int tid = threadIdx.x;
    if (blockIdx.x >= NGEMMB) {
        // ---- pack: contiguous 32KB stream per wave (R13-proven shape) ----
        const int wid = (blockIdx.x - NGEMMB) * 4 + (tid >> 6);
        const int lane = tid & 63;
        const int wpw = PKWORDS / 4096;
        const size_t w0 = (size_t)wid * wpw;
        for (int i = 0; i < wpw; i += 4) {
            int v0 = adj[((w0 + i) << 6) | lane];
            int v1 = adj[((w0 + i + 1) << 6) | lane];
            int v2 = adj[((w0 + i + 2) << 6) | lane];
            int v3 = adj[((w0 + i + 3) << 6) | lane];
            unsigned long long m0 = __ballot(v0 > 0);
            unsigned long long m1 = __ballot(v1 > 0);
            unsigned long long m2 = __ballot(v2 > 0);
            unsigned long long m3 = __ballot(v3 > 0);
            if (lane == 0) {
                pk[w0 + i] = m0;
                pk[w0 + i + 1] = m1;
                pk[w0 + i + 2] = m2;
                pk[w0 + i + 3] = m3;
            }
        }
        return;
    }
    // ---- gemm: Wh + s1 + EF=(2^s2', 2^0.2s2') + s2max (R13-proven) ----
    const int lane = tid & 63;
    const int w = tid >> 6;
    const int lo = lane & 15, g = lane >> 4;
    const int i0 = (blockIdx.x * 4 + w) * 16;
    const int bf16w = wave_sniff((const unsigned short*)hraw);

    short8 ahi[4], alo[4];
    if (bf16w) {
        const short* h16 = (const short*)hraw;
#pragma unroll
        for (int kc = 0; kc < 4; ++kc) {
            ahi[kc] = *(const short8*)(h16 + (size_t)(i0 + lo) * NF + kc * 32 + g * 8);
            alo[kc] = (short8){0, 0, 0, 0, 0, 0, 0, 0};
        }
    } else {
        const float* hf = (const float*)hraw;
#pragma unroll
        for (int kc = 0; kc < 4; ++kc) {
            const float* p = hf + (size_t)(i0 + lo) * NF + kc * 32 + g * 8;
            float4v x0 = *(const float4v*)(p);
            float4v x1 = *(const float4v*)(p + 4);
            short8 h8, l8;
#pragma unroll
            for (int q = 0; q < 4; ++q) {
                unsigned short u0 = f2bf(x0[q]);
                h8[q] = (short)u0;
                l8[q] = (short)f2bf(x0[q] - bf2f(u0));
                unsigned short u1 = f2bf(x1[q]);
                h8[q + 4] = (short)u1;
                l8[q + 4] = (short)f2bf(x1[q] - bf2f(u1));
            }
            ahi[kc] = h8;
            alo[kc] = l8;
        }
    }

    f32x4 acc[8];
#pragma unroll
    for (int t = 0; t < 8; ++t) acc[t] = (f32x4){0.f, 0.f, 0.f, 0.f};
#pragma unroll
    for (int t = 0; t < 8; ++t) {
#pragma unroll
        for (int kc = 0; kc < 4; ++kc) {
            const size_t boff = (size_t)(lo + 16 * t) * NF + kc * 32 + g * 8;
            short8 bhi = *(const short8*)(WThi + boff);
            short8 blo = *(const short8*)(WTlo + boff);
            acc[t] = __builtin_amdgcn_mfma_f32_16x16x32_bf16(ahi[kc], bhi, acc[t], 0, 0, 0);
            acc[t] = __builtin_amdgcn_mfma_f32_16x16x32_bf16(ahi[kc], blo, acc[t], 0, 0, 0);
            acc[t] = __builtin_amdgcn_mfma_f32_16x16x32_bf16(alo[kc], bhi, acc[t], 0, 0, 0);
        }
    }

    const int b = i0 >> 11;
    const int n0 = i0 & 2047;
    short* wt = WhT + (size_t)b * NF * NN;
#pragma unroll
    for (int t = 0; t < 8; ++t) {
        ushort4v u;
#pragma unroll
        for (int r = 0; r < 4; ++r) u[r] = f2bf(acc[t][r]);
        *(ushort4v*)(wt + (size_t)(lo + 16 * t) * NN + n0 + g * 4) = u;
    }

    float a1f[8], a2f[8];
#pragma unroll
    for (int t = 0; t < 8; ++t) {
        a1f[t] = a1s[lo + 16 * t];
        a2f[t] = a2s[lo + 16 * t];
    }
    float wm = -1e30f;
#pragma unroll
    for (int r = 0; r < 4; ++r) {
        float d1 = 0.f, d2 = 0.f;
#pragma unroll
        for (int t = 0; t < 8; ++t) {
            float wv = acc[t][r];
            d1 += wv * a1f[t];
            d2 += wv * a2f[t];
        }
#pragma unroll
        for (int off = 1; off < 16; off <<= 1) {
            d1 += __shfl_xor(d1, off);
            d2 += __shfl_xor(d2, off);
        }
        if (lo == 0) {
            s1[i0 + g * 4 + r] = d1;
            float2v ef;
            ef[0] = fexp2(d2);
            ef[1] = fexp2(0.2f * d2);
            *(float2v*)(EF + (size_t)(i0 + g * 4 + r) * 2) = ef;
        }
        wm = fmaxf(wm, d2);
    }
    wm = fmaxf(wm, __shfl_xor(wm, 16));
    wm = fmaxf(wm, __shfl_xor(wm, 32));
    if (lane == 0) atomicMax(&s2mkey[b], fkey(wm));
}

// ---------------- k_attn: factorized softmax + PV, batch-aligned XCD map ----
// gid decode: b = gid&7 (XCD-aligned under round-robin dispatch -> per-XCD
// working set = one batch: WhT 1MB + pk 512KB, L2-resident), blk=(gid>>3)&31,
// js = gid>>8. pO partials stored bf16 (halves partial traffic).
template <int FINAL, int JS>
__global__ __launch_bounds__(256, 4) void k_attn(const unsigned long long* __restrict__ pk,
                                                 const float* __restrict__ s1,
                                                 const float* __restrict__ EF,
                                                 const unsigned* __restrict__ s2mkey,
                                                 const short* __restrict__ WhT,
                                                 const void* __restrict__ hraw,
                                                 void* __restrict__ out,
                                                 unsigned short* __restrict__ pO,
                                                 float* __restrict__ pL) {
    constexpr int JL = NN / JS;
    constexpr int NT = JL / 64;

    const int tid = threadIdx.x;
    const int lane = tid & 63, wid = tid >> 6;
    const int lo = lane & 15, g = lane >> 4;
    const int gid = blockIdx.x;
    const int b = gid & 7;
    const int blk = (gid >> 3) & 31;
    const int js = (JS > 1) ? (gid >> 8) : 0;
    const int rowbase = blk * 64 + wid * 16;
    const int row = rowbase + lo;
    const int jbeg = js * JL;

    __shared__ short lds[2][128 * 64];
    __shared__ float ldsZ[JL * 2];

    const float s1v = s1[b * NN + row];
    const float tm = s1v + funkey(s2mkey[b]);
    const float M = fmaxf(tm, 0.2f * tm);
    const float Tc = fexp2(-s1v);
    const float Ac = fexp2(s1v - M);
    const float Bc = fexp2(0.2f * s1v - M);
    const unsigned long long* pkr = pk + (size_t)(b * NN + row) * PKW + (jbeg >> 6);
    const short* vb = WhT + (size_t)b * NF * NN;

    {
        const float4v* src = (const float4v*)(EF + (size_t)(b * NN + jbeg) * 2);
        for (int i = tid; i < JL / 2; i += 256) ((float4v*)ldsZ)[i] = src[i];
    }

    const int sf = tid >> 1;
    const int sh = tid & 1;
    const short* sbase = vb + (size_t)sf * NN + jbeg + sh * 32;
    char* ldsc0 = (char*)&lds[0][0];
    char* ldsc1 = (char*)&lds[1][0];
    const unsigned swz = (unsigned)((sf & 7) << 4);
    const unsigned wb0 = (unsigned)(sf * 128 + sh * 64);
    const unsigned rsw = (unsigned)((lo & 7) << 4);

    f32x4 acc[8];
#pragma unroll
    for (int t = 0; t < 8; ++t) acc[t] = (f32x4){0.f, 0.f, 0.f, 0.f};
    float lsum = 0.f;

    {
        short8 s0 = *(const short8*)(sbase);
        short8 s1r = *(const short8*)(sbase + 8);
        short8 s2r = *(const short8*)(sbase + 16);
        short8 s3r = *(const short8*)(sbase + 24);
        *(short8*)(ldsc0 + ((wb0 + 0) ^ swz)) = s0;
        *(short8*)(ldsc0 + ((wb0 + 16) ^ swz)) = s1r;
        *(short8*)(ldsc0 + ((wb0 + 32) ^ swz)) = s2r;
        *(short8*)(ldsc0 + ((wb0 + 48) ^ swz)) = s3r;
    }
    unsigned long long mcur = pkr[0];
    __syncthreads();

    int cur = 0;
    for (int t = 0; t < NT; ++t) {
        short8 sn0, sn1, sn2, sn3;
        unsigned long long mnext = 0;
        const bool more = (t + 1 < NT);
        if (more) {
            const short* sp = sbase + (t + 1) * 64;
            sn0 = *(const short8*)(sp);
            sn1 = *(const short8*)(sp + 8);
            sn2 = *(const short8*)(sp + 16);
            sn3 = *(const short8*)(sp + 24);
            mnext = pkr[t + 1];
        }
        const char* cb = cur ? ldsc1 : ldsc0;

        short8 pa[2];
#pragma unroll
        for (int c = 0; c < 2; ++c) {
            const float4v* zp = (const float4v*)&ldsZ[((t) * 64 + c * 32 + g * 8) * 2];
            float4v w_[4];
#pragma unroll
            for (int q = 0; q < 4; ++q) w_[q] = zp[q];
            const unsigned bits = (unsigned)(mcur >> (c * 32 + g * 8)) & 0xFFu;
            float pv[8];
#pragma unroll
            for (int k = 0; k < 8; ++k) {
                float E = w_[k >> 1][(k & 1) * 2];
                float F = w_[k >> 1][(k & 1) * 2 + 1];
                bool cond = E >= Tc;
                float sel = cond ? E : F;
                float coef = cond ? Ac : Bc;
                float p = sel * coef;
                p = ((bits >> k) & 1u) ? p : 0.f;
                lsum += p;
                pv[k] = p;
            }
            unsigned r0, r1, r2, r3;
            asm("v_cvt_pk_bf16_f32 %0, %1, %2" : "=v"(r0) : "v"(pv[0]), "v"(pv[1]));
            asm("v_cvt_pk_bf16_f32 %0, %1, %2" : "=v"(r1) : "v"(pv[2]), "v"(pv[3]));
            asm("v_cvt_pk_bf16_f32 %0, %1, %2" : "=v"(r2) : "v"(pv[4]), "v"(pv[5]));
            asm("v_cvt_pk_bf16_f32 %0, %1, %2" : "=v"(r3) : "v"(pv[6]), "v"(pv[7]));
            union { unsigned u[4]; short8 s; } uu;
            uu.u[0] = r0; uu.u[1] = r1; uu.u[2] = r2; uu.u[3] = r3;
            pa[c] = uu.s;
        }

#pragma unroll
        for (int t8 = 0; t8 < 8; ++t8) {
            const unsigned rb0 = ((unsigned)((lo + 16 * t8) * 128 + g * 16)) ^ rsw;
            const unsigned rb1 = ((unsigned)((lo + 16 * t8) * 128 + 64 + g * 16)) ^ rsw;
            short8 v0 = *(const short8*)(cb + rb0);
            short8 v1 = *(const short8*)(cb + rb1);
            acc[t8] = __builtin_amdgcn_mfma_f32_16x16x32_bf16(pa[0], v0, acc[t8], 0, 0, 0);
            acc[t8] = __builtin_amdgcn_mfma_f32_16x16x32_bf16(pa[1], v1, acc[t8], 0, 0, 0);
        }

        if (more) {
            char* wb = cur ? ldsc0 : ldsc1;
            *(short8*)(wb + ((wb0 + 0) ^ swz)) = sn0;
            *(short8*)(wb + ((wb0 + 16) ^ swz)) = sn1;
            *(short8*)(wb + ((wb0 + 32) ^ swz)) = sn2;
            *(short8*)(wb + ((wb0 + 48) ^ swz)) = sn3;
            mcur = mnext;
        }
        __syncthreads();
        cur ^= 1;
    }

    lsum += __shfl_xor(lsum, 16);
    lsum += __shfl_xor(lsum, 32);

    if (FINAL) {
        const int bf16w = wave_sniff((const unsigned short*)hraw);
        float inv[4];
#pragma unroll
        for (int r = 0; r < 4; ++r) inv[r] = 1.0f / __shfl(lsum, g * 4 + r);
#pragma unroll
        for (int t8 = 0; t8 < 8; ++t8) {
#pragma unroll
            for (int r = 0; r < 4; ++r) {
                float x = acc[t8][r] * inv[r];
                float y = (x > 0.f) ? x : (fexp2(x * LOG2E) - 1.0f);
                size_t oi = ((size_t)b * NN + rowbase + g * 4 + r) * NF + lo + 16 * t8;
                if (bf16w) ((unsigned short*)out)[oi] = f2bf(y);
                else ((float*)out)[oi] = y;
            }
        }
    } else {
        const int grp = b * 128 + blk * 4 + wid;
        unsigned short* po = pO + (size_t)(grp * JS + js) * (16 * NF);
#pragma unroll
        for (int t8 = 0; t8 < 8; ++t8)
#pragma unroll
            for (int r = 0; r < 4; ++r)
                po[(g * 4 + r) * NF + lo + 16 * t8] = f2bf(acc[t8][r]);
        if (g == 0) pL[(grp * JS + js) * 16 + lo] = lsum;
    }
}

// ---------------- k_combine: merge bf16 partials, ELU, store ----------------
__global__ __launch_bounds__(256) void k_combine(const unsigned short* __restrict__ pO,
                                                 const float* __restrict__ pL,
                                                 const void* __restrict__ hraw,
                                                 void* __restrict__ out,
                                                 int jsplit) {
    const int bf16w = wave_sniff((const unsigned short*)hraw);
    int idx4 = blockIdx.x * 256 + threadIdx.x;
    int base = idx4 * 4;
    if (base >= NB * NN * NF) return;
    int col = base & 127;
    int rowg = base >> 7;
    int r = rowg & 15;
    int grp = rowg >> 4;
    float o0 = 0.f, o1 = 0.f, o2 = 0.f, o3 = 0.f;
    float l = 0.f;
    for (int js = 0; js < jsplit; ++js) {
        int task = grp * jsplit + js;
        ushort4v u = *(const ushort4v*)(pO + (size_t)task * (16 * NF) + r * NF + col);
        o0 += bf2f(u[0]); o1 += bf2f(u[1]); o2 += bf2f(u[2]); o3 += bf2f(u[3]);
        l += pL[task * 16 + r];
    }
    float inv = 1.0f / l;
    float y[4];
    float ov[4] = {o0, o1, o2, o3};
#pragma unroll
    for (int q = 0; q < 4; ++q) {
        float x = ov[q] * inv;
        y[q] = (x > 0.f) ? x : (fexp2(x * LOG2E) - 1.0f);
    }
    if (bf16w) {
        ushort4v u;
#pragma unroll
        for (int q = 0; q < 4; ++q) u[q] = f2bf(y[q]);
        *(ushort4v*)((unsigned short*)out + base) = u;
    } else {
        *(float4v*)((float*)out + base) = (float4v){y[0], y[1], y[2], y[3]};
    }
}

extern "C" void kernel_launch(void* const* d_in, const int* in_sizes, int n_in,
                              void* d_out, int out_size, void* d_ws, size_t ws_size,
                              hipStream_t stream) {
    const void* h = d_in[0];
    const int* adj = (const int*)d_in[1];
    const void* W = d_in[2];
    const void* a = d_in[3];

    char* ws = (char*)d_ws;
    auto align256 = [](size_t x) { return (x + 255) & ~(size_t)255; };
    size_t off = 0;
    short* WThi = (short*)(ws + off); off = align256(off + (size_t)128 * 128 * 2);
    short* WTlo = (short*)(ws + off); off = align256(off + (size_t)128 * 128 * 2);
    float* a1s = (float*)(ws + off);  off = align256(off + 128 * 4);
    float* a2s = (float*)(ws + off);  off = align256(off + 128 * 4);
    short* WhT = (short*)(ws + off);  off = align256(off + (size_t)NB * NF * NN * 2);
    float* s1 = (float*)(ws + off);   off = align256(off + (size_t)NB * NN * 4);
    float* EF = (float*)(ws + off);   off = align256(off + (size_t)NB * NN * 8);
    unsigned* s2mkey = (unsigned*)(ws + off); off = align256(off + NB * 4);
    unsigned long long* pk = (unsigned long long*)(ws + off);
    off = align256(off + (size_t)PKWORDS * 8);

    const int ngrp = NB * 128;
    auto need = [&](int js) {
        return off + (size_t)ngrp * js * 16 * NF * 2 + 512 + (size_t)ngrp * js * 16 * 4;
    };
    int jsplit = (ws_size >= need(4)) ? 4 : ((ws_size >= need(2)) ? 2 : 1);
    unsigned short* pO = nullptr;
    float* pL = nullptr;
    if (jsplit > 1) {
        size_t pO_bytes = (size_t)ngrp * jsplit * 16 * NF * 2;
        size_t pL_bytes = (size_t)ngrp * jsplit * 16 * 4;
        pO = (unsigned short*)(ws + off); off = align256(off + pO_bytes);
        pL = (float*)(ws + off); off = align256(off + pL_bytes);
    }

    k_prep<<<64, 256, 0, stream>>>(W, a, WThi, WTlo, a1s, a2s, s2mkey);
    k_fat<<<NGEMMB + NPACKB, 256, 0, stream>>>(adj, pk, h, WThi, WTlo, a1s, a2s,
                                               s1, EF, s2mkey, WhT);
    if (jsplit == 4) {
        k_attn<0, 4><<<NB * 32 * 4, 256, 0, stream>>>(pk, s1, EF, s2mkey, WhT, h,
                                                      d_out, pO, pL);
    } else if (jsplit == 2) {
        k_attn<0, 2><<<NB * 32 * 2, 256, 0, stream>>>(pk, s1, EF, s2mkey, WhT, h,
                                                      d_out, pO, pL);
    } else {
        k_attn<1, 1><<<NB * 32, 256, 0, stream>>>(pk, s1, EF, s2mkey, WhT, h,
                                                  d_out, nullptr, nullptr);
    }
    if (jsplit > 1) {
        int nout = NB * NN * NF;
        k_combine<<<(nout / 4 + 255) / 256, 256, 0, stream>>>(pO, pL, h, d_out, jsplit);
    }
}

// Round 18
// 72.827 us; speedup vs baseline: 3.2050x; 1.0453x over previous
//
#include <hip/hip_runtime.h>
#include <hip/hip_bf16.h>
#include <string.h>

typedef __attribute__((ext_vector_type(8))) short short8;
typedef __attribute__((ext_vector_type(4))) float f32x4;
typedef __attribute__((ext_vector_type(4))) float float4v;
typedef __attribute__((ext_vector_type(2))) float float2v;
typedef __attribute__((ext_vector_type(4))) unsigned short ushort4v;

#define LOG2E 1.44269504088896340736f
#define NB 8
#define NN 2048
#define NF 128
#define PKW (NN / 64)
#define PKWORDS (NB * NN * PKW)
#define NGEMMB 256
#define NPACKB 1024

// fast RNE f32->bf16 (finite inputs only)
static __device__ inline unsigned short f2bf(float x) {
    unsigned u = __float_as_uint(x);
    return (unsigned short)((u + 0x7FFFu + ((u >> 16) & 1u)) >> 16);
}
static __device__ inline float bf2f(unsigned short u) {
    union { unsigned u; float f; } v;
    v.u = ((unsigned)u) << 16;
    return v.f;
}
static __device__ inline float fexp2(float x) {
    float r;
    asm("v_exp_f32 %0, %1" : "=v"(r) : "v"(x));
    return r;
}
static __device__ inline unsigned fkey(float f) {
    unsigned u = __float_as_uint(f);
    return (u & 0x80000000u) ? ~u : (u | 0x80000000u);
}
static __device__ inline float funkey(unsigned k) {
    unsigned b = (k & 0x80000000u) ? (k & 0x7FFFFFFFu) : ~k;
    return __uint_as_float(b);
}
static __device__ inline int wave_sniff(const unsigned short* __restrict__ raw) {
    int lane = threadIdx.x & 63;
    int cnt = 0;
#pragma unroll
    for (int i = 0; i < 8; ++i) {
        int e = (raw[lane * 8 + i] >> 7) & 0xFF;
        cnt += (e >= 102 && e <= 139) ? 1 : 0;
    }
#pragma unroll
    for (int off = 1; off < 64; off <<= 1) cnt += __shfl_xor(cnt, off);
    return cnt >= 450;
}

// ---------------- k_prep: WT hi/lo split-transpose + a vectors + s2m init ---
__global__ __launch_bounds__(256) void k_prep(const void* __restrict__ Wraw,
                                              const void* __restrict__ araw,
                                              short* __restrict__ WThi,
                                              short* __restrict__ WTlo,
                                              float* __restrict__ a1s,
                                              float* __restrict__ a2s,
                                              unsigned* __restrict__ s2mkey) {
    const int bf16w = wave_sniff((const unsigned short*)Wraw);
    int idx = blockIdx.x * 256 + threadIdx.x;
    int k = idx >> 7, n = idx & 127;
    float x = bf16w ? bf2f(((const unsigned short*)Wraw)[idx])
                    : ((const float*)Wraw)[idx];
    unsigned short hi = f2bf(x);
    float lo = x - bf2f(hi);
    WThi[n * 128 + k] = (short)hi;
    WTlo[n * 128 + k] = (short)f2bf(lo);
    if (blockIdx.x == 0) {
        int i = threadIdx.x;
        float av = bf16w ? bf2f(((const unsigned short*)araw)[i])
                         : ((const float*)araw)[i];
        if (i < 128) a1s[i] = LOG2E * av;
        else a2s[i - 128] = LOG2E * av;
        if (i < NB) s2mkey[i] = 0u;
    }
}

// ---------------- k_fat: gemm (blocks 0..255) || pack (blocks 256..1279) ----
__global__ __launch_bounds__(256, 4) void k_fat(const int* __restrict__ adj,
                                                unsigned long long* __restrict__ pk,
                                                const void* __restrict__ hraw,
                                                const short* __restrict__ WThi,
                                                const short* __restrict__ WTlo,
                                                const float* __restrict__ a1s,
                                                const float* __restrict__ a2s,
                                                float* __restrict__ s1,
                                                float* __restrict__ EF,
                                                unsigned* __restrict__ s2mkey,
                                                short* __restrict__ WhT) {
    const int tid = threadIdx.x;
    if (blockIdx.x >= NGEMMB) {
        // ---- pack: contiguous stream per wave, 8-deep batching (R12-proven)
        const int wid = (blockIdx.x - NGEMMB) * 4 + (tid >> 6);
        const int lane = tid & 63;
        const int wpw = PKWORDS / 4096;
        const size_t w0 = (size_t)wid * wpw;
        for (int i = 0; i < wpw; i += 8) {
            int v[8];
#pragma unroll
            for (int k = 0; k < 8; ++k) v[k] = adj[((w0 + i + k) << 6) | lane];
            unsigned long long m[8];
#pragma unroll
            for (int k = 0; k < 8; ++k) m[k] = __ballot(v[k] > 0);
            if (lane == 0) {
#pragma unroll
                for (int k = 0; k < 8; ++k) pk[w0 + i + k] = m[k];
            }
        }
        return;
    }
    const int lane = tid & 63;
    const int w = tid >> 6;
    const int lo = lane & 15, g = lane >> 4;
    const int i0 = (blockIdx.x * 4 + w) * 16;
    const int bf16w = wave_sniff((const unsigned short*)hraw);

    short8 ahi[4], alo[4];
    if (bf16w) {
        const short* h16 = (const short*)hraw;
#pragma unroll
        for (int kc = 0; kc < 4; ++kc) {
            ahi[kc] = *(const short8*)(h16 + (size_t)(i0 + lo) * NF + kc * 32 + g * 8);
            alo[kc] = (short8){0, 0, 0, 0, 0, 0, 0, 0};
        }
    } else {
        const float* hf = (const float*)hraw;
#pragma unroll
        for (int kc = 0; kc < 4; ++kc) {
            const float* p = hf + (size_t)(i0 + lo) * NF + kc * 32 + g * 8;
            float4v x0 = *(const float4v*)(p);
            float4v x1 = *(const float4v*)(p + 4);
            short8 h8, l8;
#pragma unroll
            for (int q = 0; q < 4; ++q) {
                unsigned short u0 = f2bf(x0[q]);
                h8[q] = (short)u0;
                l8[q] = (short)f2bf(x0[q] - bf2f(u0));
                unsigned short u1 = f2bf(x1[q]);
                h8[q + 4] = (short)u1;
                l8[q + 4] = (short)f2bf(x1[q] - bf2f(u1));
            }
            ahi[kc] = h8;
            alo[kc] = l8;
        }
    }

    f32x4 acc[8];
#pragma unroll
    for (int t = 0; t < 8; ++t) acc[t] = (f32x4){0.f, 0.f, 0.f, 0.f};
#pragma unroll
    for (int t = 0; t < 8; ++t) {
#pragma unroll
        for (int kc = 0; kc < 4; ++kc) {
            const size_t boff = (size_t)(lo + 16 * t) * NF + kc * 32 + g * 8;
            short8 bhi = *(const short8*)(WThi + boff);
            short8 blo = *(const short8*)(WTlo + boff);
            acc[t] = __builtin_amdgcn_mfma_f32_16x16x32_bf16(ahi[kc], bhi, acc[t], 0, 0, 0);
            acc[t] = __builtin_amdgcn_mfma_f32_16x16x32_bf16(ahi[kc], blo, acc[t], 0, 0, 0);
            acc[t] = __builtin_amdgcn_mfma_f32_16x16x32_bf16(alo[kc], bhi, acc[t], 0, 0, 0);
        }
    }

    const int b = i0 >> 11;
    const int n0 = i0 & 2047;
    short* wt = WhT + (size_t)b * NF * NN;
#pragma unroll
    for (int t = 0; t < 8; ++t) {
        ushort4v u;
#pragma unroll
        for (int r = 0; r < 4; ++r) u[r] = f2bf(acc[t][r]);
        *(ushort4v*)(wt + (size_t)(lo + 16 * t) * NN + n0 + g * 4) = u;
    }

    float a1f[8], a2f[8];
#pragma unroll
    for (int t = 0; t < 8; ++t) {
        a1f[t] = a1s[lo + 16 * t];
        a2f[t] = a2s[lo + 16 * t];
    }
    float wm = -1e30f;
#pragma unroll
    for (int r = 0; r < 4; ++r) {
        float d1 = 0.f, d2 = 0.f;
#pragma unroll
        for (int t = 0; t < 8; ++t) {
            float wv = acc[t][r];
            d1 += wv * a1f[t];
            d2 += wv * a2f[t];
        }
#pragma unroll
        for (int off = 1; off < 16; off <<= 1) {
            d1 += __shfl_xor(d1, off);
            d2 += __shfl_xor(d2, off);
        }
        if (lo == 0) {
            s1[i0 + g * 4 + r] = d1;
            float2v ef;
            ef[0] = fexp2(d2);
            ef[1] = fexp2(0.2f * d2);
            *(float2v*)(EF + (size_t)(i0 + g * 4 + r) * 2) = ef;
        }
        wm = fmaxf(wm, d2);
    }
    wm = fmaxf(wm, __shfl_xor(wm, 16));
    wm = fmaxf(wm, __shfl_xor(wm, 32));
    if (lane == 0) atomicMax(&s2mkey[b], fkey(wm));
}

// ---------------- k_attn: factorized softmax + PV, batch-aligned XCD map ----
// (R16-proven, byte-identical)
template <int FINAL, int JS>
__global__ __launch_bounds__(256, 4) void k_attn(const unsigned long long* __restrict__ pk,
                                                 const float* __restrict__ s1,
                                                 const float* __restrict__ EF,
                                                 const unsigned* __restrict__ s2mkey,
                                                 const short* __restrict__ WhT,
                                                 const void* __restrict__ hraw,
                                                 void* __restrict__ out,
                                                 unsigned short* __restrict__ pO,
                                                 float* __restrict__ pL) {
    constexpr int JL = NN / JS;
    constexpr int NT = JL / 64;

    const int tid = threadIdx.x;
    const int lane = tid & 63, wid = tid >> 6;
    const int lo = lane & 15, g = lane >> 4;
    const int gid = blockIdx.x;
    const int b = gid & 7;
    const int blk = (gid >> 3) & 31;
    const int js = (JS > 1) ? (gid >> 8) : 0;
    const int rowbase = blk * 64 + wid * 16;
    const int row = rowbase + lo;
    const int jbeg = js * JL;

    __shared__ short lds[2][128 * 64];
    __shared__ float ldsZ[JL * 2];

    const float s1v = s1[b * NN + row];
    const float tm = s1v + funkey(s2mkey[b]);
    const float M = fmaxf(tm, 0.2f * tm);
    const float Tc = fexp2(-s1v);
    const float Ac = fexp2(s1v - M);
    const float Bc = fexp2(0.2f * s1v - M);
    const unsigned long long* pkr = pk + (size_t)(b * NN + row) * PKW + (jbeg >> 6);
    const short* vb = WhT + (size_t)b * NF * NN;

    {
        const float4v* src = (const float4v*)(EF + (size_t)(b * NN + jbeg) * 2);
        for (int i = tid; i < JL / 2; i += 256) ((float4v*)ldsZ)[i] = src[i];
    }

    const int sf = tid >> 1;
    const int sh = tid & 1;
    const short* sbase = vb + (size_t)sf * NN + jbeg + sh * 32;
    char* ldsc0 = (char*)&lds[0][0];
    char* ldsc1 = (char*)&lds[1][0];
    const unsigned swz = (unsigned)((sf & 7) << 4);
    const unsigned wb0 = (unsigned)(sf * 128 + sh * 64);
    const unsigned rsw = (unsigned)((lo & 7) << 4);

    f32x4 acc[8];
#pragma unroll
    for (int t = 0; t < 8; ++t) acc[t] = (f32x4){0.f, 0.f, 0.f, 0.f};
    float lsum = 0.f;

    {
        short8 s0 = *(const short8*)(sbase);
        short8 s1r = *(const short8*)(sbase + 8);
        short8 s2r = *(const short8*)(sbase + 16);
        short8 s3r = *(const short8*)(sbase + 24);
        *(short8*)(ldsc0 + ((wb0 + 0) ^ swz)) = s0;
        *(short8*)(ldsc0 + ((wb0 + 16) ^ swz)) = s1r;
        *(short8*)(ldsc0 + ((wb0 + 32) ^ swz)) = s2r;
        *(short8*)(ldsc0 + ((wb0 + 48) ^ swz)) = s3r;
    }
    unsigned long long mcur = pkr[0];
    __syncthreads();

    int cur = 0;
    for (int t = 0; t < NT; ++t) {
        short8 sn0, sn1, sn2, sn3;
        unsigned long long mnext = 0;
        const bool more = (t + 1 < NT);
        if (more) {
            const short* sp = sbase + (t + 1) * 64;
            sn0 = *(const short8*)(sp);
            sn1 = *(const short8*)(sp + 8);
            sn2 = *(const short8*)(sp + 16);
            sn3 = *(const short8*)(sp + 24);
            mnext = pkr[t + 1];
        }
        const char* cb = cur ? ldsc1 : ldsc0;

        short8 pa[2];
#pragma unroll
        for (int c = 0; c < 2; ++c) {
            const float4v* zp = (const float4v*)&ldsZ[((t) * 64 + c * 32 + g * 8) * 2];
            float4v w_[4];
#pragma unroll
            for (int q = 0; q < 4; ++q) w_[q] = zp[q];
            const unsigned bits = (unsigned)(mcur >> (c * 32 + g * 8)) & 0xFFu;
            float pv[8];
#pragma unroll
            for (int k = 0; k < 8; ++k) {
                float E = w_[k >> 1][(k & 1) * 2];
                float F = w_[k >> 1][(k & 1) * 2 + 1];
                bool cond = E >= Tc;
                float sel = cond ? E : F;
                float coef = cond ? Ac : Bc;
                float p = sel * coef;
                p = ((bits >> k) & 1u) ? p : 0.f;
                lsum += p;
                pv[k] = p;
            }
            unsigned r0, r1, r2, r3;
            asm("v_cvt_pk_bf16_f32 %0, %1, %2" : "=v"(r0) : "v"(pv[0]), "v"(pv[1]));
            asm("v_cvt_pk_bf16_f32 %0, %1, %2" : "=v"(r1) : "v"(pv[2]), "v"(pv[3]));
            asm("v_cvt_pk_bf16_f32 %0, %1, %2" : "=v"(r2) : "v"(pv[4]), "v"(pv[5]));
            asm("v_cvt_pk_bf16_f32 %0, %1, %2" : "=v"(r3) : "v"(pv[6]), "v"(pv[7]));
            union { unsigned u[4]; short8 s; } uu;
            uu.u[0] = r0; uu.u[1] = r1; uu.u[2] = r2; uu.u[3] = r3;
            pa[c] = uu.s;
        }

#pragma unroll
        for (int t8 = 0; t8 < 8; ++t8) {
            const unsigned rb0 = ((unsigned)((lo + 16 * t8) * 128 + g * 16)) ^ rsw;
            const unsigned rb1 = ((unsigned)((lo + 16 * t8) * 128 + 64 + g * 16)) ^ rsw;
            short8 v0 = *(const short8*)(cb + rb0);
            short8 v1 = *(const short8*)(cb + rb1);
            acc[t8] = __builtin_amdgcn_mfma_f32_16x16x32_bf16(pa[0], v0, acc[t8], 0, 0, 0);
            acc[t8] = __builtin_amdgcn_mfma_f32_16x16x32_bf16(pa[1], v1, acc[t8], 0, 0, 0);
        }

        if (more) {
            char* wb = cur ? ldsc0 : ldsc1;
            *(short8*)(wb + ((wb0 + 0) ^ swz)) = sn0;
            *(short8*)(wb + ((wb0 + 16) ^ swz)) = sn1;
            *(short8*)(wb + ((wb0 + 32) ^ swz)) = sn2;
            *(short8*)(wb + ((wb0 + 48) ^ swz)) = sn3;
            mcur = mnext;
        }
        __syncthreads();
        cur ^= 1;
    }

    lsum += __shfl_xor(lsum, 16);
    lsum += __shfl_xor(lsum, 32);

    if (FINAL) {
        const int bf16w = wave_sniff((const unsigned short*)hraw);
        float inv[4];
#pragma unroll
        for (int r = 0; r < 4; ++r) inv[r] = 1.0f / __shfl(lsum, g * 4 + r);
#pragma unroll
        for (int t8 = 0; t8 < 8; ++t8) {
#pragma unroll
            for (int r = 0; r < 4; ++r) {
                float x = acc[t8][r] * inv[r];
                float y = (x > 0.f) ? x : (fexp2(x * LOG2E) - 1.0f);
                size_t oi = ((size_t)b * NN + rowbase + g * 4 + r) * NF + lo + 16 * t8;
                if (bf16w) ((unsigned short*)out)[oi] = f2bf(y);
                else ((float*)out)[oi] = y;
            }
        }
    } else {
        const int grp = b * 128 + blk * 4 + wid;
        unsigned short* po = pO + (size_t)(grp * JS + js) * (16 * NF);
#pragma unroll
        for (int t8 = 0; t8 < 8; ++t8)
#pragma unroll
            for (int r = 0; r < 4; ++r)
                po[(g * 4 + r) * NF + lo + 16 * t8] = f2bf(acc[t8][r]);
        if (g == 0) pL[(grp * JS + js) * 16 + lo] = lsum;
    }
}

// ---------------- k_combine: merge bf16 partials, ELU, store ----------------
__global__ __launch_bounds__(256) void k_combine(const unsigned short* __restrict__ pO,
                                                 const float* __restrict__ pL,
                                                 const void* __restrict__ hraw,
                                                 void* __restrict__ out,
                                                 int jsplit) {
    const int bf16w = wave_sniff((const unsigned short*)hraw);
    int idx4 = blockIdx.x * 256 + threadIdx.x;
    int base = idx4 * 4;
    if (base >= NB * NN * NF) return;
    int col = base & 127;
    int rowg = base >> 7;
    int r = rowg & 15;
    int grp = rowg >> 4;
    float o0 = 0.f, o1 = 0.f, o2 = 0.f, o3 = 0.f;
    float l = 0.f;
    for (int js = 0; js < jsplit; ++js) {
        int task = grp * jsplit + js;
        ushort4v u = *(const ushort4v*)(pO + (size_t)task * (16 * NF) + r * NF + col);
        o0 += bf2f(u[0]); o1 += bf2f(u[1]); o2 += bf2f(u[2]); o3 += bf2f(u[3]);
        l += pL[task * 16 + r];
    }
    float inv = 1.0f / l;
    float y[4];
    float ov[4] = {o0, o1, o2, o3};
#pragma unroll
    for (int q = 0; q < 4; ++q) {
        float x = ov[q] * inv;
        y[q] = (x > 0.f) ? x : (fexp2(x * LOG2E) - 1.0f);
    }
    if (bf16w) {
        ushort4v u;
#pragma unroll
        for (int q = 0; q < 4; ++q) u[q] = f2bf(y[q]);
        *(ushort4v*)((unsigned short*)out + base) = u;
    } else {
        *(float4v*)((float*)out + base) = (float4v){y[0], y[1], y[2], y[3]};
    }
}

extern "C" void kernel_launch(void* const* d_in, const int* in_sizes, int n_in,
                              void* d_out, int out_size, void* d_ws, size_t ws_size,
                              hipStream_t stream) {
    const void* h = d_in[0];
    const int* adj = (const int*)d_in[1];
    const void* W = d_in[2];
    const void* a = d_in[3];

    char* ws = (char*)d_ws;
    auto align256 = [](size_t x) { return (x + 255) & ~(size_t)255; };
    size_t off = 0;
    short* WThi = (short*)(ws + off); off = align256(off + (size_t)128 * 128 * 2);
    short* WTlo = (short*)(ws + off); off = align256(off + (size_t)128 * 128 * 2);
    float* a1s = (float*)(ws + off);  off = align256(off + 128 * 4);
    float* a2s = (float*)(ws + off);  off = align256(off + 128 * 4);
    short* WhT = (short*)(ws + off);  off = align256(off + (size_t)NB * NF * NN * 2);
    float* s1 = (float*)(ws + off);   off = align256(off + (size_t)NB * NN * 4);
    float* EF = (float*)(ws + off);   off = align256(off + (size_t)NB * NN * 8);
    unsigned* s2mkey = (unsigned*)(ws + off); off = align256(off + NB * 4);
    unsigned long long* pk = (unsigned long long*)(ws + off);
    off = align256(off + (size_t)PKWORDS * 8);

    const int ngrp = NB * 128;
    auto need = [&](int js) {
        return off + (size_t)ngrp * js * 16 * NF * 2 + 512 + (size_t)ngrp * js * 16 * 4;
    };
    int jsplit = (ws_size >= need(4)) ? 4 : ((ws_size >= need(2)) ? 2 : 1);
    unsigned short* pO = nullptr;
    float* pL = nullptr;
    if (jsplit > 1) {
        size_t pO_bytes = (size_t)ngrp * jsplit * 16 * NF * 2;
        size_t pL_bytes = (size_t)ngrp * jsplit * 16 * 4;
        pO = (unsigned short*)(ws + off); off = align256(off + pO_bytes);
        pL = (float*)(ws + off); off = align256(off + pL_bytes);
    }

    k_prep<<<64, 256, 0, stream>>>(W, a, WThi, WTlo, a1s, a2s, s2mkey);
    k_fat<<<NGEMMB + NPACKB, 256, 0, stream>>>(adj, pk, h, WThi, WTlo, a1s, a2s,
                                               s1, EF, s2mkey, WhT);
    if (jsplit == 4) {
        k_attn<0, 4><<<NB * 32 * 4, 256, 0, stream>>>(pk, s1, EF, s2mkey, WhT, h,
                                                      d_out, pO, pL);
    } else if (jsplit == 2) {
        k_attn<0, 2><<<NB * 32 * 2, 256, 0, stream>>>(pk, s1, EF, s2mkey, WhT, h,
                                                      d_out, pO, pL);
    } else {
        k_attn<1, 1><<<NB * 32, 256, 0, stream>>>(pk, s1, EF, s2mkey, WhT, h,
                                                  d_out, nullptr, nullptr);
    }
    if (jsplit > 1) {
        int nout = NB * NN * NF;
        k_combine<<<(nout / 4 + 255) / 256, 256, 0, stream>>>(pO, pL, h, d_out, jsplit);
    }
}

// Round 19
// 72.520 us; speedup vs baseline: 3.2185x; 1.0042x over previous
//
#include <hip/hip_runtime.h>
#include <hip/hip_bf16.h>
#include <string.h>

typedef __attribute__((ext_vector_type(8))) short short8;
typedef __attribute__((ext_vector_type(4))) float f32x4;
typedef __attribute__((ext_vector_type(4))) float float4v;
typedef __attribute__((ext_vector_type(2))) float float2v;
typedef __attribute__((ext_vector_type(4))) unsigned short ushort4v;

#define LOG2E 1.44269504088896340736f
#define NB 8
#define NN 2048
#define NF 128
#define PKW (NN / 64)
#define PKWORDS (NB * NN * PKW)
#define NGEMMB 256
#define NPACKB 1024

// fast RNE f32->bf16 (finite inputs only)
static __device__ inline unsigned short f2bf(float x) {
    unsigned u = __float_as_uint(x);
    return (unsigned short)((u + 0x7FFFu + ((u >> 16) & 1u)) >> 16);
}
static __device__ inline float bf2f(unsigned short u) {
    union { unsigned u; float f; } v;
    v.u = ((unsigned)u) << 16;
    return v.f;
}
static __device__ inline float fexp2(float x) {
    float r;
    asm("v_exp_f32 %0, %1" : "=v"(r) : "v"(x));
    return r;
}
static __device__ inline unsigned fkey(float f) {
    unsigned u = __float_as_uint(f);
    return (u & 0x80000000u) ? ~u : (u | 0x80000000u);
}
static __device__ inline float funkey(unsigned k) {
    unsigned b = (k & 0x80000000u) ? (k & 0x7FFFFFFFu) : ~k;
    return __uint_as_float(b);
}
static __device__ inline int wave_sniff(const unsigned short* __restrict__ raw) {
    int lane = threadIdx.x & 63;
    int cnt = 0;
#pragma unroll
    for (int i = 0; i < 8; ++i) {
        int e = (raw[lane * 8 + i] >> 7) & 0xFF;
        cnt += (e >= 102 && e <= 139) ? 1 : 0;
    }
#pragma unroll
    for (int off = 1; off < 64; off <<= 1) cnt += __shfl_xor(cnt, off);
    return cnt >= 450;
}

// ---------------- k_prep: WT hi/lo split-transpose + a vectors + s2m init ---
__global__ __launch_bounds__(256) void k_prep(const void* __restrict__ Wraw,
                                              const void* __restrict__ araw,
                                              short* __restrict__ WThi,
                                              short* __restrict__ WTlo,
                                              float* __restrict__ a1s,
                                              float* __restrict__ a2s,
                                              unsigned* __restrict__ s2mkey) {
    const int bf16w = wave_sniff((const unsigned short*)Wraw);
    int idx = blockIdx.x * 256 + threadIdx.x;
    int k = idx >> 7, n = idx & 127;
    float x = bf16w ? bf2f(((const unsigned short*)Wraw)[idx])
                    : ((const float*)Wraw)[idx];
    unsigned short hi = f2bf(x);
    float lo = x - bf2f(hi);
    WThi[n * 128 + k] = (short)hi;
    WTlo[n * 128 + k] = (short)f2bf(lo);
    if (blockIdx.x == 0) {
        int i = threadIdx.x;
        float av = bf16w ? bf2f(((const unsigned short*)araw)[i])
                         : ((const float*)araw)[i];
        if (i < 128) a1s[i] = LOG2E * av;
        else a2s[i - 128] = LOG2E * av;
        if (i < NB) s2mkey[i] = 0u;
    }
}

// ---------------- k_fat: gemm (blocks 0..255) || pack (blocks 256..1279) ----
__global__ __launch_bounds__(256, 4) void k_fat(const int* __restrict__ adj,
                                                unsigned long long* __restrict__ pk,
                                                const void* __restrict__ hraw,
                                                const short* __restrict__ WThi,
                                                const short* __restrict__ WTlo,
                                                const float* __restrict__ a1s,
                                                const float* __restrict__ a2s,
                                                float* __restrict__ s1,
                                                float* __restrict__ EF,
                                                unsigned* __restrict__ s2mkey,
                                                short* __restrict__ WhT) {
    const int tid = threadIdx.x;
    if (blockIdx.x >= NGEMMB) {
        // ---- pack: contiguous stream per wave, 8-deep batching ----
        const int wid = (blockIdx.x - NGEMMB) * 4 + (tid >> 6);
        const int lane = tid & 63;
        const int wpw = PKWORDS / 4096;
        const size_t w0 = (size_t)wid * wpw;
        for (int i = 0; i < wpw; i += 8) {
            int v[8];
#pragma unroll
            for (int k = 0; k < 8; ++k) v[k] = adj[((w0 + i + k) << 6) | lane];
            unsigned long long m[8];
#pragma unroll
            for (int k = 0; k < 8; ++k) m[k] = __ballot(v[k] > 0);
            if (lane == 0) {
#pragma unroll
                for (int k = 0; k < 8; ++k) pk[w0 + i + k] = m[k];
            }
        }
        return;
    }
    const int lane = tid & 63;
    const int w = tid >> 6;
    const int lo = lane & 15, g = lane >> 4;
    const int i0 = (blockIdx.x * 4 + w) * 16;
    const int bf16w = wave_sniff((const unsigned short*)hraw);

    short8 ahi[4], alo[4];
    if (bf16w) {
        const short* h16 = (const short*)hraw;
#pragma unroll
        for (int kc = 0; kc < 4; ++kc) {
            ahi[kc] = *(const short8*)(h16 + (size_t)(i0 + lo) * NF + kc * 32 + g * 8);
            alo[kc] = (short8){0, 0, 0, 0, 0, 0, 0, 0};
        }
    } else {
        const float* hf = (const float*)hraw;
#pragma unroll
        for (int kc = 0; kc < 4; ++kc) {
            const float* p = hf + (size_t)(i0 + lo) * NF + kc * 32 + g * 8;
            float4v x0 = *(const float4v*)(p);
            float4v x1 = *(const float4v*)(p + 4);
            short8 h8, l8;
#pragma unroll
            for (int q = 0; q < 4; ++q) {
                unsigned short u0 = f2bf(x0[q]);
                h8[q] = (short)u0;
                l8[q] = (short)f2bf(x0[q] - bf2f(u0));
                unsigned short u1 = f2bf(x1[q]);
                h8[q + 4] = (short)u1;
                l8[q + 4] = (short)f2bf(x1[q] - bf2f(u1));
            }
            ahi[kc] = h8;
            alo[kc] = l8;
        }
    }

    f32x4 acc[8];
#pragma unroll
    for (int t = 0; t < 8; ++t) acc[t] = (f32x4){0.f, 0.f, 0.f, 0.f};
#pragma unroll
    for (int t = 0; t < 8; ++t) {
#pragma unroll
        for (int kc = 0; kc < 4; ++kc) {
            const size_t boff = (size_t)(lo + 16 * t) * NF + kc * 32 + g * 8;
            short8 bhi = *(const short8*)(WThi + boff);
            short8 blo = *(const short8*)(WTlo + boff);
            acc[t] = __builtin_amdgcn_mfma_f32_16x16x32_bf16(ahi[kc], bhi, acc[t], 0, 0, 0);
            acc[t] = __builtin_amdgcn_mfma_f32_16x16x32_bf16(ahi[kc], blo, acc[t], 0, 0, 0);
            acc[t] = __builtin_amdgcn_mfma_f32_16x16x32_bf16(alo[kc], bhi, acc[t], 0, 0, 0);
        }
    }

    const int b = i0 >> 11;
    const int n0 = i0 & 2047;
    short* wt = WhT + (size_t)b * NF * NN;
#pragma unroll
    for (int t = 0; t < 8; ++t) {
        ushort4v u;
#pragma unroll
        for (int r = 0; r < 4; ++r) u[r] = f2bf(acc[t][r]);
        *(ushort4v*)(wt + (size_t)(lo + 16 * t) * NN + n0 + g * 4) = u;
    }

    float a1f[8], a2f[8];
#pragma unroll
    for (int t = 0; t < 8; ++t) {
        a1f[t] = a1s[lo + 16 * t];
        a2f[t] = a2s[lo + 16 * t];
    }
    float wm = -1e30f;
#pragma unroll
    for (int r = 0; r < 4; ++r) {
        float d1 = 0.f, d2 = 0.f;
#pragma unroll
        for (int t = 0; t < 8; ++t) {
            float wv = acc[t][r];
            d1 += wv * a1f[t];
            d2 += wv * a2f[t];
        }
#pragma unroll
        for (int off = 1; off < 16; off <<= 1) {
            d1 += __shfl_xor(d1, off);
            d2 += __shfl_xor(d2, off);
        }
        if (lo == 0) {
            s1[i0 + g * 4 + r] = d1;
            float2v ef;
            ef[0] = fexp2(d2);
            ef[1] = fexp2(0.2f * d2);
            *(float2v*)(EF + (size_t)(i0 + g * 4 + r) * 2) = ef;
        }
        wm = fmaxf(wm, d2);
    }
    wm = fmaxf(wm, __shfl_xor(wm, 16));
    wm = fmaxf(wm, __shfl_xor(wm, 32));
    if (lane == 0) atomicMax(&s2mkey[b], fkey(wm));
}

// ---------------- k_attn: factorized softmax + PV, batch-aligned XCD map ----
// R18 + T5: s_setprio(1) around the ds_read+MFMA cluster (cross-block wave
// role diversity: 4 blocks/CU at different phases -> scheduler favors MFMA).
template <int FINAL, int JS>
__global__ __launch_bounds__(256, 4) void k_attn(const unsigned long long* __restrict__ pk,
                                                 const float* __restrict__ s1,
                                                 const float* __restrict__ EF,
                                                 const unsigned* __restrict__ s2mkey,
                                                 const short* __restrict__ WhT,
                                                 const void* __restrict__ hraw,
                                                 void* __restrict__ out,
                                                 unsigned short* __restrict__ pO,
                                                 float* __restrict__ pL) {
    constexpr int JL = NN / JS;
    constexpr int NT = JL / 64;

    const int tid = threadIdx.x;
    const int lane = tid & 63, wid = tid >> 6;
    const int lo = lane & 15, g = lane >> 4;
    const int gid = blockIdx.x;
    const int b = gid & 7;
    const int blk = (gid >> 3) & 31;
    const int js = (JS > 1) ? (gid >> 8) : 0;
    const int rowbase = blk * 64 + wid * 16;
    const int row = rowbase + lo;
    const int jbeg = js * JL;

    __shared__ short lds[2][128 * 64];
    __shared__ float ldsZ[JL * 2];

    const float s1v = s1[b * NN + row];
    const float tm = s1v + funkey(s2mkey[b]);
    const float M = fmaxf(tm, 0.2f * tm);
    const float Tc = fexp2(-s1v);
    const float Ac = fexp2(s1v - M);
    const float Bc = fexp2(0.2f * s1v - M);
    const unsigned long long* pkr = pk + (size_t)(b * NN + row) * PKW + (jbeg >> 6);
    const short* vb = WhT + (size_t)b * NF * NN;

    {
        const float4v* src = (const float4v*)(EF + (size_t)(b * NN + jbeg) * 2);
        for (int i = tid; i < JL / 2; i += 256) ((float4v*)ldsZ)[i] = src[i];
    }

    const int sf = tid >> 1;
    const int sh = tid & 1;
    const short* sbase = vb + (size_t)sf * NN + jbeg + sh * 32;
    char* ldsc0 = (char*)&lds[0][0];
    char* ldsc1 = (char*)&lds[1][0];
    const unsigned swz = (unsigned)((sf & 7) << 4);
    const unsigned wb0 = (unsigned)(sf * 128 + sh * 64);
    const unsigned rsw = (unsigned)((lo & 7) << 4);

    f32x4 acc[8];
#pragma unroll
    for (int t = 0; t < 8; ++t) acc[t] = (f32x4){0.f, 0.f, 0.f, 0.f};
    float lsum = 0.f;

    {
        short8 s0 = *(const short8*)(sbase);
        short8 s1r = *(const short8*)(sbase + 8);
        short8 s2r = *(const short8*)(sbase + 16);
        short8 s3r = *(const short8*)(sbase + 24);
        *(short8*)(ldsc0 + ((wb0 + 0) ^ swz)) = s0;
        *(short8*)(ldsc0 + ((wb0 + 16) ^ swz)) = s1r;
        *(short8*)(ldsc0 + ((wb0 + 32) ^ swz)) = s2r;
        *(short8*)(ldsc0 + ((wb0 + 48) ^ swz)) = s3r;
    }
    unsigned long long mcur = pkr[0];
    __syncthreads();

    int cur = 0;
    for (int t = 0; t < NT; ++t) {
        short8 sn0, sn1, sn2, sn3;
        unsigned long long mnext = 0;
        const bool more = (t + 1 < NT);
        if (more) {
            const short* sp = sbase + (t + 1) * 64;
            sn0 = *(const short8*)(sp);
            sn1 = *(const short8*)(sp + 8);
            sn2 = *(const short8*)(sp + 16);
            sn3 = *(const short8*)(sp + 24);
            mnext = pkr[t + 1];
        }
        const char* cb = cur ? ldsc1 : ldsc0;

        short8 pa[2];
#pragma unroll
        for (int c = 0; c < 2; ++c) {
            const float4v* zp = (const float4v*)&ldsZ[((t) * 64 + c * 32 + g * 8) * 2];
            float4v w_[4];
#pragma unroll
            for (int q = 0; q < 4; ++q) w_[q] = zp[q];
            const unsigned bits = (unsigned)(mcur >> (c * 32 + g * 8)) & 0xFFu;
            float pv[8];
#pragma unroll
            for (int k = 0; k < 8; ++k) {
                float E = w_[k >> 1][(k & 1) * 2];
                float F = w_[k >> 1][(k & 1) * 2 + 1];
                bool cond = E >= Tc;
                float sel = cond ? E : F;
                float coef = cond ? Ac : Bc;
                float p = sel * coef;
                p = ((bits >> k) & 1u) ? p : 0.f;
                lsum += p;
                pv[k] = p;
            }
            unsigned r0, r1, r2, r3;
            asm("v_cvt_pk_bf16_f32 %0, %1, %2" : "=v"(r0) : "v"(pv[0]), "v"(pv[1]));
            asm("v_cvt_pk_bf16_f32 %0, %1, %2" : "=v"(r1) : "v"(pv[2]), "v"(pv[3]));
            asm("v_cvt_pk_bf16_f32 %0, %1, %2" : "=v"(r2) : "v"(pv[4]), "v"(pv[5]));
            asm("v_cvt_pk_bf16_f32 %0, %1, %2" : "=v"(r3) : "v"(pv[6]), "v"(pv[7]));
            union { unsigned u[4]; short8 s; } uu;
            uu.u[0] = r0; uu.u[1] = r1; uu.u[2] = r2; uu.u[3] = r3;
            pa[c] = uu.s;
        }

        __builtin_amdgcn_s_setprio(1);
#pragma unroll
        for (int t8 = 0; t8 < 8; ++t8) {
            const unsigned rb0 = ((unsigned)((lo + 16 * t8) * 128 + g * 16)) ^ rsw;
            const unsigned rb1 = ((unsigned)((lo + 16 * t8) * 128 + 64 + g * 16)) ^ rsw;
            short8 v0 = *(const short8*)(cb + rb0);
            short8 v1 = *(const short8*)(cb + rb1);
            acc[t8] = __builtin_amdgcn_mfma_f32_16x16x32_bf16(pa[0], v0, acc[t8], 0, 0, 0);
            acc[t8] = __builtin_amdgcn_mfma_f32_16x16x32_bf16(pa[1], v1, acc[t8], 0, 0, 0);
        }
        __builtin_amdgcn_s_setprio(0);

        if (more) {
            char* wb = cur ? ldsc0 : ldsc1;
            *(short8*)(wb + ((wb0 + 0) ^ swz)) = sn0;
            *(short8*)(wb + ((wb0 + 16) ^ swz)) = sn1;
            *(short8*)(wb + ((wb0 + 32) ^ swz)) = sn2;
            *(short8*)(wb + ((wb0 + 48) ^ swz)) = sn3;
            mcur = mnext;
        }
        __syncthreads();
        cur ^= 1;
    }

    lsum += __shfl_xor(lsum, 16);
    lsum += __shfl_xor(lsum, 32);

    if (FINAL) {
        const int bf16w = wave_sniff((const unsigned short*)hraw);
        float inv[4];
#pragma unroll
        for (int r = 0; r < 4; ++r) inv[r] = 1.0f / __shfl(lsum, g * 4 + r);
#pragma unroll
        for (int t8 = 0; t8 < 8; ++t8) {
#pragma unroll
            for (int r = 0; r < 4; ++r) {
                float x = acc[t8][r] * inv[r];
                float y = (x > 0.f) ? x : (fexp2(x * LOG2E) - 1.0f);
                size_t oi = ((size_t)b * NN + rowbase + g * 4 + r) * NF + lo + 16 * t8;
                if (bf16w) ((unsigned short*)out)[oi] = f2bf(y);
                else ((float*)out)[oi] = y;
            }
        }
    } else {
        const int grp = b * 128 + blk * 4 + wid;
        unsigned short* po = pO + (size_t)(grp * JS + js) * (16 * NF);
#pragma unroll
        for (int t8 = 0; t8 < 8; ++t8)
#pragma unroll
            for (int r = 0; r < 4; ++r)
                po[(g * 4 + r) * NF + lo + 16 * t8] = f2bf(acc[t8][r]);
        if (g == 0) pL[(grp * JS + js) * 16 + lo] = lsum;
    }
}

// ---------------- k_combine: merge bf16 partials, ELU, store ----------------
__global__ __launch_bounds__(256) void k_combine(const unsigned short* __restrict__ pO,
                                                 const float* __restrict__ pL,
                                                 const void* __restrict__ hraw,
                                                 void* __restrict__ out,
                                                 int jsplit) {
    const int bf16w = wave_sniff((const unsigned short*)hraw);
    int idx4 = blockIdx.x * 256 + threadIdx.x;
    int base = idx4 * 4;
    if (base >= NB * NN * NF) return;
    int col = base & 127;
    int rowg = base >> 7;
    int r = rowg & 15;
    int grp = rowg >> 4;
    float o0 = 0.f, o1 = 0.f, o2 = 0.f, o3 = 0.f;
    float l = 0.f;
    for (int js = 0; js < jsplit; ++js) {
        int task = grp * jsplit + js;
        ushort4v u = *(const ushort4v*)(pO + (size_t)task * (16 * NF) + r * NF + col);
        o0 += bf2f(u[0]); o1 += bf2f(u[1]); o2 += bf2f(u[2]); o3 += bf2f(u[3]);
        l += pL[task * 16 + r];
    }
    float inv = 1.0f / l;
    float y[4];
    float ov[4] = {o0, o1, o2, o3};
#pragma unroll
    for (int q = 0; q < 4; ++q) {
        float x = ov[q] * inv;
        y[q] = (x > 0.f) ? x : (fexp2(x * LOG2E) - 1.0f);
    }
    if (bf16w) {
        ushort4v u;
#pragma unroll
        for (int q = 0; q < 4; ++q) u[q] = f2bf(y[q]);
        *(ushort4v*)((unsigned short*)out + base) = u;
    } else {
        *(float4v*)((float*)out + base) = (float4v){y[0], y[1], y[2], y[3]};
    }
}

extern "C" void kernel_launch(void* const* d_in, const int* in_sizes, int n_in,
                              void* d_out, int out_size, void* d_ws, size_t ws_size,
                              hipStream_t stream) {
    const void* h = d_in[0];
    const int* adj = (const int*)d_in[1];
    const void* W = d_in[2];
    const void* a = d_in[3];

    char* ws = (char*)d_ws;
    auto align256 = [](size_t x) { return (x + 255) & ~(size_t)255; };
    size_t off = 0;
    short* WThi = (short*)(ws + off); off = align256(off + (size_t)128 * 128 * 2);
    short* WTlo = (short*)(ws + off); off = align256(off + (size_t)128 * 128 * 2);
    float* a1s = (float*)(ws + off);  off = align256(off + 128 * 4);
    float* a2s = (float*)(ws + off);  off = align256(off + 128 * 4);
    short* WhT = (short*)(ws + off);  off = align256(off + (size_t)NB * NF * NN * 2);
    float* s1 = (float*)(ws + off);   off = align256(off + (size_t)NB * NN * 4);
    float* EF = (float*)(ws + off);   off = align256(off + (size_t)NB * NN * 8);
    unsigned* s2mkey = (unsigned*)(ws + off); off = align256(off + NB * 4);
    unsigned long long* pk = (unsigned long long*)(ws + off);
    off = align256(off + (size_t)PKWORDS * 8);

    const int ngrp = NB * 128;
    auto need = [&](int js) {
        return off + (size_t)ngrp * js * 16 * NF * 2 + 512 + (size_t)ngrp * js * 16 * 4;
    };
    int jsplit = (ws_size >= need(4)) ? 4 : ((ws_size >= need(2)) ? 2 : 1);
    unsigned short* pO = nullptr;
    float* pL = nullptr;
    if (jsplit > 1) {
        size_t pO_bytes = (size_t)ngrp * jsplit * 16 * NF * 2;
        size_t pL_bytes = (size_t)ngrp * jsplit * 16 * 4;
        pO = (unsigned short*)(ws + off); off = align256(off + pO_bytes);
        pL = (float*)(ws + off); off = align256(off + pL_bytes);
    }

    k_prep<<<64, 256, 0, stream>>>(W, a, WThi, WTlo, a1s, a2s, s2mkey);
    k_fat<<<NGEMMB + NPACKB, 256, 0, stream>>>(adj, pk, h, WThi, WTlo, a1s, a2s,
                                               s1, EF, s2mkey, WhT);
    if (jsplit == 4) {
        k_attn<0, 4><<<NB * 32 * 4, 256, 0, stream>>>(pk, s1, EF, s2mkey, WhT, h,
                                                      d_out, pO, pL);
    } else if (jsplit == 2) {
        k_attn<0, 2><<<NB * 32 * 2, 256, 0, stream>>>(pk, s1, EF, s2mkey, WhT, h,
                                                      d_out, pO, pL);
    } else {
        k_attn<1, 1><<<NB * 32, 256, 0, stream>>>(pk, s1, EF, s2mkey, WhT, h,
                                                  d_out, nullptr, nullptr);
    }
    if (jsplit > 1) {
        int nout = NB * NN * NF;
        k_combine<<<(nout / 4 + 255) / 256, 256, 0, stream>>>(pO, pL, h, d_out, jsplit);
    }
}